// Round 7
// baseline (21438.632 us; speedup 1.0000x reference)
//
#include <hip/hip_runtime.h>

// Problem constants
#define BB 16
#define NN 2048
#define KK 20

#define NEG_INF (-3.402823466e+38f)
#define DNEG (-1.0e300)

// ---------------------------------------------------------------------------
// Weight prep: transposed fp64 copies of all weights + biases (exact casts).
// Layout (doubles) in wd:
//   w1tlo[3][64]   @0       w1thi[3][64]   @192     w2t  [64][64]  @384
//   w3tlo[64][64]  @4480    w3thi[64][64]  @8576    w4t  [64][64]  @12672
//   w5tlo[64][64]  @16768   w5thi[64][64]  @20864
//   b1d@24960 b2d@25024 b3d@25088 b4d@25152 b5d@25216   (64 each)
// ---------------------------------------------------------------------------
__global__ void prep_wd(const float* __restrict__ w1, const float* __restrict__ b1,
                        const float* __restrict__ w2, const float* __restrict__ b2,
                        const float* __restrict__ w3, const float* __restrict__ b3,
                        const float* __restrict__ w4, const float* __restrict__ b4,
                        const float* __restrict__ w5, const float* __restrict__ b5,
                        double* __restrict__ wd) {
    int t = threadIdx.x;
    for (int i = t; i < 192; i += 256) {
        int c = i >> 6, j = i & 63;
        wd[i]       = (double)w1[j * 6 + c];
        wd[192 + i] = (double)w1[j * 6 + 3 + c];
    }
    for (int i = t; i < 4096; i += 256) {
        int a = i >> 6, q = i & 63;
        wd[384 + i]   = (double)w2[q * 64 + a];
        wd[4480 + i]  = (double)w3[q * 128 + a];
        wd[8576 + i]  = (double)w3[q * 128 + 64 + a];
        wd[12672 + i] = (double)w4[q * 64 + a];
        wd[16768 + i] = (double)w5[q * 128 + a];
        wd[20864 + i] = (double)w5[q * 128 + 64 + a];
    }
    for (int i = t; i < 64; i += 256) {
        wd[24960 + i] = (double)b1[i];
        wd[25024 + i] = (double)b2[i];
        wd[25088 + i] = (double)b3[i];
        wd[25152 + i] = (double)b4[i];
        wd[25216 + i] = (double)b5[i];
    }
}

// ---------------------------------------------------------------------------
// Top-20 selection over 2048 f32 candidates in a per-wave LDS row.
// Stable: exact ties -> lowest index (matches np stable argsort / lax.top_k).
// ---------------------------------------------------------------------------
__device__ __forceinline__ void top2_upd(float v, int g, float& av, int& ai,
                                         float& bv, int& bi) {
    bool gta = v > av;
    bool gtb = v > bv;
    float nbv = gta ? av : (gtb ? v : bv);
    int   nbi = gta ? ai : (gtb ? g : bi);
    av = gta ? v : av;
    ai = gta ? g : ai;
    bv = nbv;
    bi = nbi;
}

__device__ __forceinline__ void topk20_run(float* vrow, int lane, float av, int ai,
                                           float bv, int bi, int* outp) {
    int myout = 0;
    #pragma unroll 1
    for (int it = 0; it < 20; ++it) {
        float wv = av;
        #pragma unroll
        for (int d = 32; d; d >>= 1) wv = fmaxf(wv, __shfl_xor(wv, d));
        unsigned long long bal = __ballot(av == wv);
        int widx;
        if (__popcll(bal) == 1) {
            widx = __shfl(ai, __ffsll(bal) - 1);
        } else {  // exact tie across lanes: lowest global index wins
            int tt = (av == wv) ? ai : 0x7fffffff;
            #pragma unroll
            for (int d = 32; d; d >>= 1) tt = min(tt, __shfl_xor(tt, d));
            widx = tt;
        }
        if (lane == it) myout = widx;
        if (lane == 0) vrow[widx] = NEG_INF;   // remove winner
        if (ai == widx) { av = bv; ai = bi; bv = NEG_INF; bi = 0x7fffffff; }
        if (av == NEG_INF) {                   // rare: lane's top-2 exhausted
            ai = 0x7fffffff; bv = NEG_INF; bi = 0x7fffffff;
            #pragma unroll 1
            for (int s = 0; s < 32; ++s) {
                int col = s * 64 + lane;
                top2_upd(vrow[col], col, av, ai, bv, bi);
            }
        }
    }
    if (lane < 20) outp[lane] = myout;
}

// ---------------------------------------------------------------------------
// knn1: numpy-f32 mirror of pd = -xx - (-2*(xt@x)) - xx.T on raw x (C=3).
// xx: squares rounded, summed sequentially ascending c.
// dot: sgemm-style FMA chain ascending c.  All contraction disabled.
// ---------------------------------------------------------------------------
__global__ void knn1_k(const float* __restrict__ x, int* __restrict__ idx) {
    __shared__ float vlds[2][2048];
    int lane = threadIdx.x & 63, w = threadIdx.x >> 6;
    int b = blockIdx.y, r = blockIdx.x * 2 + w;
    const float* xb = x + (size_t)b * 3 * NN;
    float rx = xb[r], ry = xb[NN + r], rz = xb[2 * NN + r];
    float xxi = __fadd_rn(__fadd_rn(__fmul_rn(rx, rx), __fmul_rn(ry, ry)),
                          __fmul_rn(rz, rz));
    float* vrow = vlds[w];
    float av = NEG_INF, bv = NEG_INF;
    int ai = 0x7fffffff, bi = 0x7fffffff;
    #pragma unroll 1
    for (int s = 0; s < 32; ++s) {
        int col = s * 64 + lane;
        float cx = xb[col], cy = xb[NN + col], cz = xb[2 * NN + col];
        float xxj = __fadd_rn(__fadd_rn(__fmul_rn(cx, cx), __fmul_rn(cy, cy)),
                              __fmul_rn(cz, cz));
        float dot = fmaf(rz, cz, fmaf(ry, cy, __fmul_rn(rx, cx)));
        float inner = __fmul_rn(-2.f, dot);
        float t1 = __fsub_rn(-xxj, inner);
        float nd = __fsub_rn(t1, xxi);
        vrow[col] = nd;
        top2_upd(nd, col, av, ai, bv, bi);
    }
    topk20_run(vrow, lane, av, ai, bv, bi, idx + ((size_t)b * NN + r) * KK);
}

// xx for a 64-channel slice: squares rounded, sequential ascending-c sum.
__global__ void norms23_k(const float* __restrict__ x123t, int coff,
                          float* __restrict__ nrm) {
    int t = blockIdx.x * 256 + threadIdx.x;   // 32768 points
    const float* r = x123t + (size_t)t * 192 + coff;
    float acc = 0.f;
    #pragma unroll 1
    for (int c = 0; c < 64; ++c)
        acc = __fadd_rn(acc, __fmul_rn(r[c], r[c]));
    nrm[t] = acc;
}

// knn2/3: same numpy-f32 mirror on a 64-channel slice of f32 x123t.
__global__ void knn23_k(const float* __restrict__ x123t, int coff,
                        const float* __restrict__ nrm, int* __restrict__ idx) {
    __shared__ float vlds[2][2048];
    __shared__ float rowf[2][64];
    int lane = threadIdx.x & 63, w = threadIdx.x >> 6;
    int b = blockIdx.y, r = blockIdx.x * 2 + w;
    const float* rp = x123t + ((size_t)b * NN + r) * 192 + coff;
    rowf[w][lane] = rp[lane];                  // stage row r (same-wave LDS)
    const float* nb = nrm + (size_t)b * NN;
    float xxi = nb[r];
    float* vrow = vlds[w];
    float av = NEG_INF, bv = NEG_INF;
    int ai = 0x7fffffff, bi = 0x7fffffff;
    #pragma unroll 1
    for (int s = 0; s < 32; ++s) {
        int col = s * 64 + lane;
        const float* cp = x123t + ((size_t)b * NN + col) * 192 + coff;
        float acc = 0.f;                       // FMA chain, ascending c
        #pragma unroll
        for (int c = 0; c < 64; c += 4) {
            float4 q = *(const float4*)(cp + c);
            acc = fmaf(rowf[w][c + 0], q.x, acc);
            acc = fmaf(rowf[w][c + 1], q.y, acc);
            acc = fmaf(rowf[w][c + 2], q.z, acc);
            acc = fmaf(rowf[w][c + 3], q.w, acc);
        }
        float inner = __fmul_rn(-2.f, acc);
        float t1 = __fsub_rn(-nb[col], inner);
        float nd = __fsub_rn(t1, xxi);
        vrow[col] = nd;
        top2_upd(nd, col, av, ai, bv, bi);
    }
    topk20_run(vrow, lane, av, ai, bv, bi, idx + ((size_t)b * NN + r) * KK);
}

// ---------------------------------------------------------------------------
// EdgeConv blocks, per-edge fp64 math (within 1 ulp-f32 of any f32 conv).
// Wave per point, lane = channel. Writes d_out slab (f32) + x123t (f32).
// ---------------------------------------------------------------------------
__global__ void conv1_k(const float* __restrict__ x, const int* __restrict__ idxb,
                        const double* __restrict__ wd, float* __restrict__ dout,
                        float* __restrict__ x123t) {
    __shared__ double h1buf[4][64];
    int lane = threadIdx.x & 63, w = threadIdx.x >> 6;
    int p = blockIdx.x * 4 + w;
    int b = p >> 11, n = p & 2047;
    const float* xb = x + (size_t)b * 3 * NN;
    double c0 = xb[n], c1 = xb[NN + n], c2 = xb[2 * NN + n];
    const double* w2t = wd + 384;
    double bb1 = wd[24960 + lane];
    double bb2 = wd[25024 + lane];
    double wl0 = wd[0 * 64 + lane], wl1 = wd[1 * 64 + lane], wl2 = wd[2 * 64 + lane];
    double wh0 = wd[192 + 0 * 64 + lane], wh1 = wd[192 + 1 * 64 + lane], wh2 = wd[192 + 2 * 64 + lane];
    const int* ip = idxb + (size_t)p * KK;
    double m = DNEG;
    #pragma unroll 1
    for (int kk = 0; kk < KK; ++kk) {
        int nb = ip[kk];
        double n0 = xb[nb], n1 = xb[NN + nb], n2 = xb[2 * NN + nb];
        double h1 = bb1;                       // lane = j
        h1 = fma(wl0, n0 - c0, h1); h1 = fma(wh0, c0, h1);
        h1 = fma(wl1, n1 - c1, h1); h1 = fma(wh1, c1, h1);
        h1 = fma(wl2, n2 - c2, h1); h1 = fma(wh2, c2, h1);
        h1buf[w][lane] = h1;
        double h2 = bb2;                       // lane = o
        #pragma unroll
        for (int j = 0; j < 64; ++j)
            h2 = fma(w2t[j * 64 + lane], h1buf[w][j], h2);
        m = fmax(m, h2);
    }
    dout[((size_t)b * 192 + 0 + lane) * NN + n] = (float)m;
    x123t[((size_t)b * NN + n) * 192 + 0 + lane] = (float)m;
}

__global__ void conv2_k(const float* __restrict__ x123t, const int* __restrict__ idxb,
                        const double* __restrict__ wd, float* __restrict__ dout,
                        float* __restrict__ x123t_o) {
    __shared__ double h1buf[4][64];
    __shared__ double cbuf[4][64];
    int lane = threadIdx.x & 63, w = threadIdx.x >> 6;
    int p = blockIdx.x * 4 + w;
    int b = p >> 11, n = p & 2047;
    const double* w3lo = wd + 4480;
    const double* w3hi = wd + 8576;
    const double* w4t  = wd + 12672;
    double bb3 = wd[25088 + lane];
    double bb4 = wd[25152 + lane];
    cbuf[w][lane] = (double)x123t[((size_t)b * NN + n) * 192 + lane];   // ctr = x1
    const int* ip = idxb + (size_t)p * KK;
    double m = DNEG;
    #pragma unroll 1
    for (int kk = 0; kk < KK; ++kk) {
        int nb = ip[kk];
        const float* np_ = x123t + ((size_t)b * NN + nb) * 192;
        double h1 = bb3;                       // lane = j
        #pragma unroll 1
        for (int c = 0; c < 64; ++c) {
            double ctr = cbuf[w][c];
            double nc = (double)np_[c];
            h1 = fma(w3lo[c * 64 + lane], nc - ctr, h1);
            h1 = fma(w3hi[c * 64 + lane], ctr, h1);
        }
        h1buf[w][lane] = h1;
        double h2 = bb4;                       // lane = o
        #pragma unroll
        for (int j = 0; j < 64; ++j)
            h2 = fma(w4t[j * 64 + lane], h1buf[w][j], h2);
        m = fmax(m, h2);
    }
    dout[((size_t)b * 192 + 64 + lane) * NN + n] = (float)m;
    x123t_o[((size_t)b * NN + n) * 192 + 64 + lane] = (float)m;
}

__global__ void conv3_k(const float* __restrict__ x123t, const int* __restrict__ idxb,
                        const double* __restrict__ wd, float* __restrict__ dout,
                        float* __restrict__ x123t_o) {
    __shared__ double cbuf[4][64];
    int lane = threadIdx.x & 63, w = threadIdx.x >> 6;
    int p = blockIdx.x * 4 + w;
    int b = p >> 11, n = p & 2047;
    const double* w5lo = wd + 16768;
    const double* w5hi = wd + 20864;
    double bb5 = wd[25216 + lane];
    cbuf[w][lane] = (double)x123t[((size_t)b * NN + n) * 192 + 64 + lane];  // ctr = x2
    const int* ip = idxb + (size_t)p * KK;
    double m = DNEG;
    #pragma unroll 1
    for (int kk = 0; kk < KK; ++kk) {
        int nb = ip[kk];
        const float* np_ = x123t + ((size_t)b * NN + nb) * 192 + 64;
        double h = bb5;                        // lane = o
        #pragma unroll 1
        for (int c = 0; c < 64; ++c) {
            double ctr = cbuf[w][c];
            double nc = (double)np_[c];
            h = fma(w5lo[c * 64 + lane], nc - ctr, h);
            h = fma(w5hi[c * 64 + lane], ctr, h);
        }
        m = fmax(m, h);
    }
    dout[((size_t)b * 192 + 128 + lane) * NN + n] = (float)m;
    x123t_o[((size_t)b * NN + n) * 192 + 128 + lane] = (float)m;
}

// ---------------------------------------------------------------------------
// Final conv1d (1024x192), fp64 accumulate, fused per-64-n max; then reduce.
// ---------------------------------------------------------------------------
__global__ __launch_bounds__(256, 2) void w6_k(const float* __restrict__ x123t,
                                               const float* __restrict__ w6,
                                               float* __restrict__ partial6) {
    int lane = threadIdx.x & 63;
    int wid = blockIdx.x * 4 + (threadIdx.x >> 6);
    int ntile = wid & 31, ot = (wid >> 5) & 15, b = wid >> 9;
    int n = ntile * 64 + lane;
    const float* xp = x123t + (size_t)(b * NN + n) * 192;
    float xr[192];
    #pragma unroll
    for (int c = 0; c < 192; c += 4) {
        float4 q = *(const float4*)(xp + c);
        xr[c] = q.x; xr[c + 1] = q.y; xr[c + 2] = q.z; xr[c + 3] = q.w;
    }
    float red = 0.f;
    #pragma unroll 1
    for (int o = 0; o < 64; ++o) {
        const float* wr = w6 + (size_t)(ot * 64 + o) * 192;
        double s0 = 0, s1 = 0, s2 = 0, s3 = 0;
        #pragma unroll
        for (int c = 0; c < 192; c += 4) {
            s0 = fma((double)wr[c + 0], (double)xr[c + 0], s0);
            s1 = fma((double)wr[c + 1], (double)xr[c + 1], s1);
            s2 = fma((double)wr[c + 2], (double)xr[c + 2], s2);
            s3 = fma((double)wr[c + 3], (double)xr[c + 3], s3);
        }
        double wm = (s0 + s1) + (s2 + s3);
        #pragma unroll
        for (int d = 32; d; d >>= 1) wm = fmax(wm, __shfl_xor(wm, d));
        red = (lane == o) ? (float)wm : red;
    }
    partial6[((size_t)b * 1024 + ot * 64 + lane) * 32 + ntile] = red;
}

__global__ void final_k(const float* __restrict__ partial6, const float* __restrict__ b6,
                        float* __restrict__ dout) {
    int t = blockIdx.x * 256 + threadIdx.x;  // < 16*1024
    int o = t & 1023;
    float m = NEG_INF;
    #pragma unroll 1
    for (int nt = 0; nt < 32; ++nt) m = fmaxf(m, partial6[(size_t)t * 32 + nt]);
    dout[(size_t)BB * 192 * NN + t] = m + b6[o];
}

// ---------------------------------------------------------------------------
extern "C" void kernel_launch(void* const* d_in, const int* in_sizes, int n_in,
                              void* d_out_, int out_size, void* d_ws, size_t ws_size,
                              hipStream_t stream) {
    (void)in_sizes; (void)n_in; (void)out_size; (void)ws_size;
    const float* x  = (const float*)d_in[0];
    const float* w1 = (const float*)d_in[1];
    const float* b1 = (const float*)d_in[2];
    const float* w2 = (const float*)d_in[3];
    const float* b2 = (const float*)d_in[4];
    const float* w3 = (const float*)d_in[5];
    const float* b3 = (const float*)d_in[6];
    const float* w4 = (const float*)d_in[7];
    const float* b4 = (const float*)d_in[8];
    const float* w5 = (const float*)d_in[9];
    const float* b5 = (const float*)d_in[10];
    const float* w6 = (const float*)d_in[11];
    const float* b6 = (const float*)d_in[12];
    float* dout = (float*)d_out_;

    char* ws = (char*)d_ws;
    float*  x123t    = (float*)(ws + 0);           // 25,165,824 B
    int*    idxb     = (int*)(ws + 25165824);      //  2,621,440 B
    double* wd       = (double*)(ws + 27787264);   //    202,240 B
    float*  nrm      = (float*)(ws + 27989504);    //    131,072 B
    float*  partial6 = (float*)(ws + 28120576);    //  2,097,152 B
    // total ~30.2 MB of workspace

    prep_wd<<<1, 256, 0, stream>>>(w1, b1, w2, b2, w3, b3, w4, b4, w5, b5, wd);

    // ---- block 1 ----
    knn1_k<<<dim3(1024, BB), 128, 0, stream>>>(x, idxb);
    conv1_k<<<8192, 256, 0, stream>>>(x, idxb, wd, dout, x123t);

    // ---- block 2 ----
    norms23_k<<<128, 256, 0, stream>>>(x123t, 0, nrm);
    knn23_k<<<dim3(1024, BB), 128, 0, stream>>>(x123t, 0, nrm, idxb);
    conv2_k<<<8192, 256, 0, stream>>>(x123t, idxb, wd, dout, x123t);

    // ---- block 3 ----
    norms23_k<<<128, 256, 0, stream>>>(x123t, 64, nrm);
    knn23_k<<<dim3(1024, BB), 128, 0, stream>>>(x123t, 64, nrm, idxb);
    conv3_k<<<8192, 256, 0, stream>>>(x123t, idxb, wd, dout, x123t);

    // ---- final conv1d + global max ----
    w6_k<<<2048, 256, 0, stream>>>(x123t, w6, partial6);
    final_k<<<64, 256, 0, stream>>>(partial6, b6, dout);
}

// Round 8
// 7905.151 us; speedup vs baseline: 2.7120x; 2.7120x over previous
//
#include <hip/hip_runtime.h>

// Problem constants
#define BB 16
#define NN 2048
#define KK 20

#define NEG_INF (-3.402823466e+38f)
#define DNEG (-1.0e300)

// ---------------------------------------------------------------------------
// Weight prep: transposed f32 copies (exact). Float offsets in wb:
//   w1tlo[3][64]@0  w1thi[3][64]@192  w2t[64][64]@384
//   w3lo[64][64]@4480  w3hi[64][64]@8576  w4t[64][64]@12672
//   w5lo[64][64]@16768 w5hi[64][64]@20864      (total 24960 floats)
// ---------------------------------------------------------------------------
__global__ void prep_wf(const float* __restrict__ w1, const float* __restrict__ w2,
                        const float* __restrict__ w3, const float* __restrict__ w4,
                        const float* __restrict__ w5, float* __restrict__ wb) {
    int t = threadIdx.x;
    for (int i = t; i < 192; i += 256) {
        int c = i >> 6, j = i & 63;
        wb[i]       = w1[j * 6 + c];
        wb[192 + i] = w1[j * 6 + 3 + c];
    }
    for (int i = t; i < 4096; i += 256) {
        int a = i >> 6, q = i & 63;
        wb[384 + i]   = w2[q * 64 + a];        // w2t[j=a][o=q]
        wb[4480 + i]  = w3[q * 128 + a];       // w3lo[c=a][j=q]
        wb[8576 + i]  = w3[q * 128 + 64 + a];  // w3hi[c=a][j=q]
        wb[12672 + i] = w4[q * 64 + a];        // w4t[j=a][o=q]
        wb[16768 + i] = w5[q * 128 + a];       // w5lo[c=a][o=q]
        wb[20864 + i] = w5[q * 128 + 64 + a];  // w5hi[c=a][o=q]
    }
}

// ---------------------------------------------------------------------------
// Top-20 selection over 2048 f32 candidates in a per-wave LDS row.
// FROZEN (passing arithmetic): stable ties -> lowest index.
// ---------------------------------------------------------------------------
__device__ __forceinline__ void top2_upd(float v, int g, float& av, int& ai,
                                         float& bv, int& bi) {
    bool gta = v > av;
    bool gtb = v > bv;
    float nbv = gta ? av : (gtb ? v : bv);
    int   nbi = gta ? ai : (gtb ? g : bi);
    av = gta ? v : av;
    ai = gta ? g : ai;
    bv = nbv;
    bi = nbi;
}

__device__ __forceinline__ void topk20_run(float* vrow, int lane, float av, int ai,
                                           float bv, int bi, int* outp) {
    int myout = 0;
    #pragma unroll 1
    for (int it = 0; it < 20; ++it) {
        float wv = av;
        #pragma unroll
        for (int d = 32; d; d >>= 1) wv = fmaxf(wv, __shfl_xor(wv, d));
        unsigned long long bal = __ballot(av == wv);
        int widx;
        if (__popcll(bal) == 1) {
            widx = __shfl(ai, __ffsll(bal) - 1);
        } else {  // exact tie across lanes: lowest global index wins
            int tt = (av == wv) ? ai : 0x7fffffff;
            #pragma unroll
            for (int d = 32; d; d >>= 1) tt = min(tt, __shfl_xor(tt, d));
            widx = tt;
        }
        if (lane == it) myout = widx;
        if (lane == 0) vrow[widx] = NEG_INF;   // remove winner
        if (ai == widx) { av = bv; ai = bi; bv = NEG_INF; bi = 0x7fffffff; }
        if (av == NEG_INF) {                   // rare: lane's top-2 exhausted
            ai = 0x7fffffff; bv = NEG_INF; bi = 0x7fffffff;
            #pragma unroll 1
            for (int s = 0; s < 32; ++s) {
                int col = s * 64 + lane;
                top2_upd(vrow[col], col, av, ai, bv, bi);
            }
        }
    }
    if (lane < 20) outp[lane] = myout;
}

// ---------------------------------------------------------------------------
// knn1: numpy-f32 mirror of pd = -xx - (-2*(xt@x)) - xx.T on raw x (C=3).
// FROZEN arithmetic.
// ---------------------------------------------------------------------------
__global__ void knn1_k(const float* __restrict__ x, int* __restrict__ idx) {
    __shared__ float vlds[2][2048];
    int lane = threadIdx.x & 63, w = threadIdx.x >> 6;
    int b = blockIdx.y, r = blockIdx.x * 2 + w;
    const float* xb = x + (size_t)b * 3 * NN;
    float rx = xb[r], ry = xb[NN + r], rz = xb[2 * NN + r];
    float xxi = __fadd_rn(__fadd_rn(__fmul_rn(rx, rx), __fmul_rn(ry, ry)),
                          __fmul_rn(rz, rz));
    float* vrow = vlds[w];
    float av = NEG_INF, bv = NEG_INF;
    int ai = 0x7fffffff, bi = 0x7fffffff;
    #pragma unroll 1
    for (int s = 0; s < 32; ++s) {
        int col = s * 64 + lane;
        float cx = xb[col], cy = xb[NN + col], cz = xb[2 * NN + col];
        float xxj = __fadd_rn(__fadd_rn(__fmul_rn(cx, cx), __fmul_rn(cy, cy)),
                              __fmul_rn(cz, cz));
        float dot = fmaf(rz, cz, fmaf(ry, cy, __fmul_rn(rx, cx)));
        float inner = __fmul_rn(-2.f, dot);
        float t1 = __fsub_rn(-xxj, inner);
        float nd = __fsub_rn(t1, xxi);
        vrow[col] = nd;
        top2_upd(nd, col, av, ai, bv, bi);
    }
    topk20_run(vrow, lane, av, ai, bv, bi, idx + ((size_t)b * NN + r) * KK);
}

// xx for a 64-channel slice: squares rounded, sequential ascending-c sum. FROZEN.
__global__ void norms23_k(const float* __restrict__ x123t, int coff,
                          float* __restrict__ nrm) {
    int t = blockIdx.x * 256 + threadIdx.x;   // 32768 points
    const float* r = x123t + (size_t)t * 192 + coff;
    float acc = 0.f;
    #pragma unroll 1
    for (int c = 0; c < 64; ++c)
        acc = __fadd_rn(acc, __fmul_rn(r[c], r[c]));
    nrm[t] = acc;
}

// knn2/3: same numpy-f32 mirror on a 64-channel slice of f32 x123t. FROZEN.
__global__ void knn23_k(const float* __restrict__ x123t, int coff,
                        const float* __restrict__ nrm, int* __restrict__ idx) {
    __shared__ float vlds[2][2048];
    __shared__ float rowf[2][64];
    int lane = threadIdx.x & 63, w = threadIdx.x >> 6;
    int b = blockIdx.y, r = blockIdx.x * 2 + w;
    const float* rp = x123t + ((size_t)b * NN + r) * 192 + coff;
    rowf[w][lane] = rp[lane];                  // stage row r (same-wave LDS)
    const float* nb = nrm + (size_t)b * NN;
    float xxi = nb[r];
    float* vrow = vlds[w];
    float av = NEG_INF, bv = NEG_INF;
    int ai = 0x7fffffff, bi = 0x7fffffff;
    #pragma unroll 1
    for (int s = 0; s < 32; ++s) {
        int col = s * 64 + lane;
        const float* cp = x123t + ((size_t)b * NN + col) * 192 + coff;
        float acc = 0.f;                       // FMA chain, ascending c
        #pragma unroll
        for (int c = 0; c < 64; c += 4) {
            float4 q = *(const float4*)(cp + c);
            acc = fmaf(rowf[w][c + 0], q.x, acc);
            acc = fmaf(rowf[w][c + 1], q.y, acc);
            acc = fmaf(rowf[w][c + 2], q.z, acc);
            acc = fmaf(rowf[w][c + 3], q.w, acc);
        }
        float inner = __fmul_rn(-2.f, acc);
        float t1 = __fsub_rn(-nb[col], inner);
        float nd = __fsub_rn(t1, xxi);
        vrow[col] = nd;
        top2_upd(nd, col, av, ai, bv, bi);
    }
    topk20_run(vrow, lane, av, ai, bv, bi, idx + ((size_t)b * NN + r) * KK);
}

// ---------------------------------------------------------------------------
// EdgeConv blocks, fp64 accumulate (restructured: LDS-staged weights/rows,
// hoisted ctr-half, 4-accumulator unrolled loops). Wave = point, lane = channel.
// ---------------------------------------------------------------------------
__global__ __launch_bounds__(256) void conv1_k(const float* __restrict__ x,
        const int* __restrict__ idxb, const float* __restrict__ wb,
        const float* __restrict__ b1, const float* __restrict__ b2,
        float* __restrict__ dout, float* __restrict__ x123t) {
    __shared__ float w2t_s[4096];
    __shared__ double h1b[4][64];
    int tid = threadIdx.x, lane = tid & 63, w = tid >> 6;
    for (int i = tid; i < 4096; i += 256) w2t_s[i] = wb[384 + i];
    __syncthreads();
    int p = blockIdx.x * 4 + w, b = p >> 11, n = p & 2047;
    const float* xb = x + (size_t)b * 3 * NN;
    double c0 = (double)xb[n], c1 = (double)xb[NN + n], c2 = (double)xb[2 * NN + n];
    double wl0 = (double)wb[0 * 64 + lane], wl1 = (double)wb[1 * 64 + lane],
           wl2 = (double)wb[2 * 64 + lane];
    double hc = (double)b1[lane];
    hc = fma((double)wb[192 + 0 * 64 + lane], c0, hc);
    hc = fma((double)wb[192 + 1 * 64 + lane], c1, hc);
    hc = fma((double)wb[192 + 2 * 64 + lane], c2, hc);
    double bb2 = (double)b2[lane];
    const int* ip = idxb + (size_t)p * KK;
    double m = DNEG;
    #pragma unroll 2
    for (int kk = 0; kk < KK; ++kk) {
        int nb = ip[kk];
        double h1 = hc;
        h1 = fma(wl0, (double)xb[nb] - c0, h1);
        h1 = fma(wl1, (double)xb[NN + nb] - c1, h1);
        h1 = fma(wl2, (double)xb[2 * NN + nb] - c2, h1);
        h1b[w][lane] = h1;
        double q0 = bb2, q1 = 0, q2 = 0, q3 = 0;
        #pragma unroll
        for (int j = 0; j < 64; j += 4) {
            q0 = fma((double)w2t_s[(j + 0) * 64 + lane], h1b[w][j + 0], q0);
            q1 = fma((double)w2t_s[(j + 1) * 64 + lane], h1b[w][j + 1], q1);
            q2 = fma((double)w2t_s[(j + 2) * 64 + lane], h1b[w][j + 2], q2);
            q3 = fma((double)w2t_s[(j + 3) * 64 + lane], h1b[w][j + 3], q3);
        }
        m = fmax(m, (q0 + q1) + (q2 + q3));
    }
    dout[((size_t)b * 192 + lane) * NN + n] = (float)m;
    x123t[((size_t)b * NN + n) * 192 + lane] = (float)m;
}

__global__ __launch_bounds__(256) void conv2_k(const float* __restrict__ x123t,
        const int* __restrict__ idxb, const float* __restrict__ wb,
        const float* __restrict__ b3, const float* __restrict__ b4,
        float* __restrict__ dout, float* __restrict__ x123t_o) {
    __shared__ float w3lo_s[4096], w4t_s[4096];
    __shared__ double cb[4][64], db[4][64], h1b[4][64];
    int tid = threadIdx.x, lane = tid & 63, w = tid >> 6;
    for (int i = tid; i < 4096; i += 256) {
        w3lo_s[i] = wb[4480 + i];
        w4t_s[i]  = wb[12672 + i];
    }
    __syncthreads();
    int p = blockIdx.x * 4 + w, b = p >> 11, n = p & 2047;
    const float* base = x123t + (size_t)b * NN * 192;
    double ctr = (double)base[(size_t)n * 192 + lane];
    cb[w][lane] = ctr;
    // hc = b3 + sum_c w3hi[c][lane]*ctr_c  (once per point; w3hi coalesced global)
    double h0 = (double)b3[lane], h1a = 0, h2a = 0, h3a = 0;
    #pragma unroll 4
    for (int c = 0; c < 64; c += 4) {
        h0  = fma((double)wb[8576 + (c + 0) * 64 + lane], cb[w][c + 0], h0);
        h1a = fma((double)wb[8576 + (c + 1) * 64 + lane], cb[w][c + 1], h1a);
        h2a = fma((double)wb[8576 + (c + 2) * 64 + lane], cb[w][c + 2], h2a);
        h3a = fma((double)wb[8576 + (c + 3) * 64 + lane], cb[w][c + 3], h3a);
    }
    double hc = (h0 + h1a) + (h2a + h3a);
    double bb4 = (double)b4[lane];
    const int* ip = idxb + (size_t)p * KK;
    double m = DNEG;
    #pragma unroll 1
    for (int kk = 0; kk < KK; ++kk) {
        int nb = ip[kk];
        db[w][lane] = (double)base[(size_t)nb * 192 + lane] - ctr;  // coalesced stage
        double a0 = hc, a1 = 0, a2 = 0, a3 = 0;
        #pragma unroll
        for (int c = 0; c < 64; c += 4) {
            a0 = fma((double)w3lo_s[(c + 0) * 64 + lane], db[w][c + 0], a0);
            a1 = fma((double)w3lo_s[(c + 1) * 64 + lane], db[w][c + 1], a1);
            a2 = fma((double)w3lo_s[(c + 2) * 64 + lane], db[w][c + 2], a2);
            a3 = fma((double)w3lo_s[(c + 3) * 64 + lane], db[w][c + 3], a3);
        }
        h1b[w][lane] = (a0 + a1) + (a2 + a3);
        double q0 = bb4, q1 = 0, q2 = 0, q3 = 0;
        #pragma unroll
        for (int j = 0; j < 64; j += 4) {
            q0 = fma((double)w4t_s[(j + 0) * 64 + lane], h1b[w][j + 0], q0);
            q1 = fma((double)w4t_s[(j + 1) * 64 + lane], h1b[w][j + 1], q1);
            q2 = fma((double)w4t_s[(j + 2) * 64 + lane], h1b[w][j + 2], q2);
            q3 = fma((double)w4t_s[(j + 3) * 64 + lane], h1b[w][j + 3], q3);
        }
        m = fmax(m, (q0 + q1) + (q2 + q3));
    }
    dout[((size_t)b * 192 + 64 + lane) * NN + n] = (float)m;
    x123t_o[((size_t)b * NN + n) * 192 + 64 + lane] = (float)m;
}

__global__ __launch_bounds__(256) void conv3_k(const float* __restrict__ x123t,
        const int* __restrict__ idxb, const float* __restrict__ wb,
        const float* __restrict__ b5,
        float* __restrict__ dout, float* __restrict__ x123t_o) {
    __shared__ float w5lo_s[4096];
    __shared__ double cb[4][64], db[4][64];
    int tid = threadIdx.x, lane = tid & 63, w = tid >> 6;
    for (int i = tid; i < 4096; i += 256) w5lo_s[i] = wb[16768 + i];
    __syncthreads();
    int p = blockIdx.x * 4 + w, b = p >> 11, n = p & 2047;
    const float* base = x123t + (size_t)b * NN * 192 + 64;  // x2 slice
    double ctr = (double)base[(size_t)n * 192 + lane];
    cb[w][lane] = ctr;
    double h0 = (double)b5[lane], h1a = 0, h2a = 0, h3a = 0;
    #pragma unroll 4
    for (int c = 0; c < 64; c += 4) {
        h0  = fma((double)wb[20864 + (c + 0) * 64 + lane], cb[w][c + 0], h0);
        h1a = fma((double)wb[20864 + (c + 1) * 64 + lane], cb[w][c + 1], h1a);
        h2a = fma((double)wb[20864 + (c + 2) * 64 + lane], cb[w][c + 2], h2a);
        h3a = fma((double)wb[20864 + (c + 3) * 64 + lane], cb[w][c + 3], h3a);
    }
    double hc = (h0 + h1a) + (h2a + h3a);
    const int* ip = idxb + (size_t)p * KK;
    double m = DNEG;
    #pragma unroll 1
    for (int kk = 0; kk < KK; ++kk) {
        int nb = ip[kk];
        db[w][lane] = (double)base[(size_t)nb * 192 + lane] - ctr;
        double a0 = hc, a1 = 0, a2 = 0, a3 = 0;
        #pragma unroll
        for (int c = 0; c < 64; c += 4) {
            a0 = fma((double)w5lo_s[(c + 0) * 64 + lane], db[w][c + 0], a0);
            a1 = fma((double)w5lo_s[(c + 1) * 64 + lane], db[w][c + 1], a1);
            a2 = fma((double)w5lo_s[(c + 2) * 64 + lane], db[w][c + 2], a2);
            a3 = fma((double)w5lo_s[(c + 3) * 64 + lane], db[w][c + 3], a3);
        }
        m = fmax(m, (a0 + a1) + (a2 + a3));
    }
    dout[((size_t)b * 192 + 128 + lane) * NN + n] = (float)m;
    x123t_o[((size_t)b * NN + n) * 192 + 128 + lane] = (float)m;
}

// ---------------------------------------------------------------------------
// Final conv1d (1024x192) as LDS-tiled f32 GEMM, 64o x 64n per block, KC=32.
// Fused per-tile max over n; cross-tile reduce in final_k.
// ---------------------------------------------------------------------------
#define KC 32
__global__ __launch_bounds__(256) void w6_k(const float* __restrict__ x123t,
                                            const float* __restrict__ w6,
                                            float* __restrict__ partial6) {
    __shared__ float xs[KC][68];
    __shared__ float wsb[KC][68];
    __shared__ float red[64][17];
    int tid = threadIdx.x;
    int ntile = blockIdx.x & 31, ot = (blockIdx.x >> 5) & 15, b = blockIdx.x >> 9;
    int n0 = ntile * 64, o0 = ot * 64;
    int ln = tid >> 2, lc = (tid & 3) * 8;
    const float* xrow = x123t + ((size_t)b * NN + n0 + ln) * 192 + lc;
    const float* wrow = w6 + (size_t)(o0 + ln) * 192 + lc;
    float acc[4][4];
    #pragma unroll
    for (int i = 0; i < 4; ++i)
        #pragma unroll
        for (int j = 0; j < 4; ++j) acc[i][j] = 0.f;
    int to = tid & 15, tn = tid >> 4;
    for (int cc = 0; cc < 192; cc += KC) {
        float4 xa = *(const float4*)(xrow + cc);
        float4 xb4 = *(const float4*)(xrow + cc + 4);
        float4 wa = *(const float4*)(wrow + cc);
        float4 wb4 = *(const float4*)(wrow + cc + 4);
        __syncthreads();
        xs[lc + 0][ln] = xa.x; xs[lc + 1][ln] = xa.y;
        xs[lc + 2][ln] = xa.z; xs[lc + 3][ln] = xa.w;
        xs[lc + 4][ln] = xb4.x; xs[lc + 5][ln] = xb4.y;
        xs[lc + 6][ln] = xb4.z; xs[lc + 7][ln] = xb4.w;
        wsb[lc + 0][ln] = wa.x; wsb[lc + 1][ln] = wa.y;
        wsb[lc + 2][ln] = wa.z; wsb[lc + 3][ln] = wa.w;
        wsb[lc + 4][ln] = wb4.x; wsb[lc + 5][ln] = wb4.y;
        wsb[lc + 6][ln] = wb4.z; wsb[lc + 7][ln] = wb4.w;
        __syncthreads();
        #pragma unroll
        for (int k = 0; k < KC; ++k) {
            float4 wv = *(const float4*)&wsb[k][to * 4];
            float4 xv = *(const float4*)&xs[k][tn * 4];
            float wr[4] = {wv.x, wv.y, wv.z, wv.w};
            float xr[4] = {xv.x, xv.y, xv.z, xv.w};
            #pragma unroll
            for (int i = 0; i < 4; ++i)
                #pragma unroll
                for (int j = 0; j < 4; ++j)
                    acc[i][j] = fmaf(wr[i], xr[j], acc[i][j]);
        }
    }
    #pragma unroll
    for (int i = 0; i < 4; ++i) {
        float mm = fmaxf(fmaxf(acc[i][0], acc[i][1]), fmaxf(acc[i][2], acc[i][3]));
        red[to * 4 + i][tn] = mm;
    }
    __syncthreads();
    if (tid < 64) {
        float mm = red[tid][0];
        #pragma unroll
        for (int t = 1; t < 16; ++t) mm = fmaxf(mm, red[tid][t]);
        partial6[((size_t)b * 1024 + o0 + tid) * 32 + ntile] = mm;
    }
}

__global__ void final_k(const float* __restrict__ partial6, const float* __restrict__ b6,
                        float* __restrict__ dout) {
    int t = blockIdx.x * 256 + threadIdx.x;  // < 16*1024
    int o = t & 1023;
    float m = NEG_INF;
    #pragma unroll 1
    for (int nt = 0; nt < 32; ++nt) m = fmaxf(m, partial6[(size_t)t * 32 + nt]);
    dout[(size_t)BB * 192 * NN + t] = m + b6[o];
}

// ---------------------------------------------------------------------------
extern "C" void kernel_launch(void* const* d_in, const int* in_sizes, int n_in,
                              void* d_out_, int out_size, void* d_ws, size_t ws_size,
                              hipStream_t stream) {
    (void)in_sizes; (void)n_in; (void)out_size; (void)ws_size;
    const float* x  = (const float*)d_in[0];
    const float* w1 = (const float*)d_in[1];
    const float* b1 = (const float*)d_in[2];
    const float* w2 = (const float*)d_in[3];
    const float* b2 = (const float*)d_in[4];
    const float* w3 = (const float*)d_in[5];
    const float* b3 = (const float*)d_in[6];
    const float* w4 = (const float*)d_in[7];
    const float* b4 = (const float*)d_in[8];
    const float* w5 = (const float*)d_in[9];
    const float* b5 = (const float*)d_in[10];
    const float* w6 = (const float*)d_in[11];
    const float* b6 = (const float*)d_in[12];
    float* dout = (float*)d_out_;

    char* ws = (char*)d_ws;
    float* x123t    = (float*)(ws + 0);           // 25,165,824 B
    int*   idxb     = (int*)(ws + 25165824);      //  2,621,440 B
    float* wbuf     = (float*)(ws + 27787264);    //     99,840 B
    float* nrm      = (float*)(ws + 27887104);    //    131,072 B
    float* partial6 = (float*)(ws + 28018176);    //  2,097,152 B
    // total ~30.1 MB of workspace

    prep_wf<<<1, 256, 0, stream>>>(w1, w2, w3, w4, w5, wbuf);

    // ---- block 1 ----
    knn1_k<<<dim3(1024, BB), 128, 0, stream>>>(x, idxb);
    conv1_k<<<8192, 256, 0, stream>>>(x, idxb, wbuf, b1, b2, dout, x123t);

    // ---- block 2 ----
    norms23_k<<<128, 256, 0, stream>>>(x123t, 0, nrm);
    knn23_k<<<dim3(1024, BB), 128, 0, stream>>>(x123t, 0, nrm, idxb);
    conv2_k<<<8192, 256, 0, stream>>>(x123t, idxb, wbuf, b3, b4, dout, x123t);

    // ---- block 3 ----
    norms23_k<<<128, 256, 0, stream>>>(x123t, 64, nrm);
    knn23_k<<<dim3(1024, BB), 128, 0, stream>>>(x123t, 64, nrm, idxb);
    conv3_k<<<8192, 256, 0, stream>>>(x123t, idxb, wbuf, b5, dout, x123t);

    // ---- final conv1d + global max ----
    w6_k<<<8192, 256, 0, stream>>>(x123t, w6, partial6);
    final_k<<<64, 256, 0, stream>>>(partial6, b6, dout);
}

// Round 9
// 5885.561 us; speedup vs baseline: 3.6426x; 1.3431x over previous
//
#include <hip/hip_runtime.h>

// Problem constants
#define BB 16
#define NN 2048
#define KK 20

#define NEG_INF (-3.402823466e+38f)
#define DNEG (-1.0e300)

// ---------------------------------------------------------------------------
// Weight prep: transposed f32 copies (exact). Float offsets in wb:
//   w1tlo[3][64]@0  w1thi[3][64]@192  w2t[64][64]@384
//   w3lo[64][64]@4480  w3hi[64][64]@8576  w4t[64][64]@12672
//   w5lo[64][64]@16768 w5hi[64][64]@20864      (total 24960 floats)
// ---------------------------------------------------------------------------
__global__ void prep_wf(const float* __restrict__ w1, const float* __restrict__ w2,
                        const float* __restrict__ w3, const float* __restrict__ w4,
                        const float* __restrict__ w5, float* __restrict__ wb) {
    int t = threadIdx.x;
    for (int i = t; i < 192; i += 256) {
        int c = i >> 6, j = i & 63;
        wb[i]       = w1[j * 6 + c];
        wb[192 + i] = w1[j * 6 + 3 + c];
    }
    for (int i = t; i < 4096; i += 256) {
        int a = i >> 6, q = i & 63;
        wb[384 + i]   = w2[q * 64 + a];        // w2t[j=a][o=q]
        wb[4480 + i]  = w3[q * 128 + a];       // w3lo[c=a][j=q]
        wb[8576 + i]  = w3[q * 128 + 64 + a];  // w3hi[c=a][j=q]
        wb[12672 + i] = w4[q * 64 + a];        // w4t[j=a][o=q]
        wb[16768 + i] = w5[q * 128 + a];       // w5lo[c=a][o=q]
        wb[20864 + i] = w5[q * 128 + 64 + a];  // w5hi[c=a][o=q]
    }
}

// ---------------------------------------------------------------------------
// Top-20 selection over 2048 f32 candidates in a per-wave LDS row (knn1 only).
// FROZEN (passing arithmetic): stable ties -> lowest index.
// ---------------------------------------------------------------------------
__device__ __forceinline__ void top2_upd(float v, int g, float& av, int& ai,
                                         float& bv, int& bi) {
    bool gta = v > av;
    bool gtb = v > bv;
    float nbv = gta ? av : (gtb ? v : bv);
    int   nbi = gta ? ai : (gtb ? g : bi);
    av = gta ? v : av;
    ai = gta ? g : ai;
    bv = nbv;
    bi = nbi;
}

__device__ __forceinline__ void topk20_run(float* vrow, int lane, float av, int ai,
                                           float bv, int bi, int* outp) {
    int myout = 0;
    #pragma unroll 1
    for (int it = 0; it < 20; ++it) {
        float wv = av;
        #pragma unroll
        for (int d = 32; d; d >>= 1) wv = fmaxf(wv, __shfl_xor(wv, d));
        unsigned long long bal = __ballot(av == wv);
        int widx;
        if (__popcll(bal) == 1) {
            widx = __shfl(ai, __ffsll(bal) - 1);
        } else {  // exact tie across lanes: lowest global index wins
            int tt = (av == wv) ? ai : 0x7fffffff;
            #pragma unroll
            for (int d = 32; d; d >>= 1) tt = min(tt, __shfl_xor(tt, d));
            widx = tt;
        }
        if (lane == it) myout = widx;
        if (lane == 0) vrow[widx] = NEG_INF;   // remove winner
        if (ai == widx) { av = bv; ai = bi; bv = NEG_INF; bi = 0x7fffffff; }
        if (av == NEG_INF) {                   // rare: lane's top-2 exhausted
            ai = 0x7fffffff; bv = NEG_INF; bi = 0x7fffffff;
            #pragma unroll 1
            for (int s = 0; s < 32; ++s) {
                int col = s * 64 + lane;
                top2_upd(vrow[col], col, av, ai, bv, bi);
            }
        }
    }
    if (lane < 20) outp[lane] = myout;
}

// ---------------------------------------------------------------------------
// knn1: numpy-f32 mirror of pd = -xx - (-2*(xt@x)) - xx.T on raw x (C=3).
// FROZEN arithmetic.
// ---------------------------------------------------------------------------
__global__ void knn1_k(const float* __restrict__ x, int* __restrict__ idx) {
    __shared__ float vlds[2][2048];
    int lane = threadIdx.x & 63, w = threadIdx.x >> 6;
    int b = blockIdx.y, r = blockIdx.x * 2 + w;
    const float* xb = x + (size_t)b * 3 * NN;
    float rx = xb[r], ry = xb[NN + r], rz = xb[2 * NN + r];
    float xxi = __fadd_rn(__fadd_rn(__fmul_rn(rx, rx), __fmul_rn(ry, ry)),
                          __fmul_rn(rz, rz));
    float* vrow = vlds[w];
    float av = NEG_INF, bv = NEG_INF;
    int ai = 0x7fffffff, bi = 0x7fffffff;
    #pragma unroll 1
    for (int s = 0; s < 32; ++s) {
        int col = s * 64 + lane;
        float cx = xb[col], cy = xb[NN + col], cz = xb[2 * NN + col];
        float xxj = __fadd_rn(__fadd_rn(__fmul_rn(cx, cx), __fmul_rn(cy, cy)),
                              __fmul_rn(cz, cz));
        float dot = fmaf(rz, cz, fmaf(ry, cy, __fmul_rn(rx, cx)));
        float inner = __fmul_rn(-2.f, dot);
        float t1 = __fsub_rn(-xxj, inner);
        float nd = __fsub_rn(t1, xxi);
        vrow[col] = nd;
        top2_upd(nd, col, av, ai, bv, bi);
    }
    topk20_run(vrow, lane, av, ai, bv, bi, idx + ((size_t)b * NN + r) * KK);
}

// xx for a 64-channel slice: squares rounded, sequential ascending-c sum. FROZEN.
__global__ void norms23_k(const float* __restrict__ x123t, int coff,
                          float* __restrict__ nrm) {
    int t = blockIdx.x * 256 + threadIdx.x;   // 32768 points
    const float* r = x123t + (size_t)t * 192 + coff;
    float acc = 0.f;
    #pragma unroll 1
    for (int c = 0; c < 64; ++c)
        acc = __fadd_rn(acc, __fmul_rn(r[c], r[c]));
    nrm[t] = acc;
}

// ---------------------------------------------------------------------------
// knn2/3 v2: reads channel-major data from dout slab (same f32 values).
// 4 waves/block, 4 rows/wave. Frozen FMA chain per (row,col): ascending-c
// single-accumulator fmaf; frozen epilogue. Selection: per-lane sorted top-8
// register lists (stable), exact global-max extraction with min-index ties,
// rare exhaustion -> exact recompute fallback (same chain).
// ---------------------------------------------------------------------------
__device__ __forceinline__ void ins8(float v, int g, float (&t)[8], int (&ix)[8]) {
    bool c0 = v > t[0], c1 = v > t[1], c2 = v > t[2], c3 = v > t[3];
    bool c4 = v > t[4], c5 = v > t[5], c6 = v > t[6], c7 = v > t[7];
    t[7] = c7 ? (c6 ? t[6] : v) : t[7];  ix[7] = c7 ? (c6 ? ix[6] : g) : ix[7];
    t[6] = c6 ? (c5 ? t[5] : v) : t[6];  ix[6] = c6 ? (c5 ? ix[5] : g) : ix[6];
    t[5] = c5 ? (c4 ? t[4] : v) : t[5];  ix[5] = c5 ? (c4 ? ix[4] : g) : ix[5];
    t[4] = c4 ? (c3 ? t[3] : v) : t[4];  ix[4] = c4 ? (c3 ? ix[3] : g) : ix[4];
    t[3] = c3 ? (c2 ? t[2] : v) : t[3];  ix[3] = c3 ? (c2 ? ix[2] : g) : ix[3];
    t[2] = c2 ? (c1 ? t[1] : v) : t[2];  ix[2] = c2 ? (c1 ? ix[1] : g) : ix[2];
    t[1] = c1 ? (c0 ? t[0] : v) : t[1];  ix[1] = c1 ? (c0 ? ix[0] : g) : ix[1];
    t[0] = c0 ? v : t[0];                ix[0] = c0 ? g : ix[0];
}

__device__ __forceinline__ void rebuild_row(const float* __restrict__ doutc,
        const float* __restrict__ nrmb, const float* rowp, float xxi,
        unsigned mask, int lane, float (&t)[8], int (&ix)[8]) {
    #pragma unroll
    for (int q = 0; q < 8; ++q) { t[q] = NEG_INF; ix[q] = 0x7fffffff; }
    #pragma unroll 1
    for (int s = 0; s < 32; ++s) {
        if ((mask >> s) & 1u) continue;
        int col = s * 64 + lane;
        float acc = 0.f;
        #pragma unroll 1
        for (int c = 0; c < 64; ++c)
            acc = fmaf(rowp[c], doutc[(size_t)c * NN + col], acc);
        float inner = __fmul_rn(-2.f, acc);
        float t1 = __fsub_rn(-nrmb[col], inner);
        float nd = __fsub_rn(t1, xxi);
        ins8(nd, col, t, ix);
    }
}

__global__ __launch_bounds__(256) void knn23g_k(const float* __restrict__ x123t,
        const float* __restrict__ dout, int coff, const float* __restrict__ nrm,
        int* __restrict__ idx) {
    __shared__ float rowst[4][4][64];
    int lane = threadIdx.x & 63, w = threadIdx.x >> 6;
    int bb = blockIdx.y;
    int r0 = blockIdx.x * 16 + w * 4;
    const float* doutc = dout + (size_t)(bb * 192 + coff) * NN;
    const float* nrmb = nrm + (size_t)bb * NN;
    float xxi[4];
    #pragma unroll
    for (int j = 0; j < 4; ++j) {
        rowst[w][j][lane] = x123t[((size_t)bb * NN + r0 + j) * 192 + coff + lane];
        xxi[j] = nrmb[r0 + j];
    }
    float tl[4][8];
    int   il[4][8];
    #pragma unroll
    for (int j = 0; j < 4; ++j)
        #pragma unroll
        for (int q = 0; q < 8; ++q) { tl[j][q] = NEG_INF; il[j][q] = 0x7fffffff; }

    #pragma unroll 1
    for (int g = 0; g < 32; ++g) {
        int col = g * 64 + lane;
        float nbv = nrmb[col];
        float a0 = 0.f, a1 = 0.f, a2 = 0.f, a3 = 0.f;
        const float* p = doutc + col;
        #pragma unroll
        for (int seg = 0; seg < 8; ++seg) {
            float4 ra0 = *(const float4*)&rowst[w][0][seg * 8];
            float4 rb0 = *(const float4*)&rowst[w][0][seg * 8 + 4];
            float4 ra1 = *(const float4*)&rowst[w][1][seg * 8];
            float4 rb1 = *(const float4*)&rowst[w][1][seg * 8 + 4];
            float4 ra2 = *(const float4*)&rowst[w][2][seg * 8];
            float4 rb2 = *(const float4*)&rowst[w][2][seg * 8 + 4];
            float4 ra3 = *(const float4*)&rowst[w][3][seg * 8];
            float4 rb3 = *(const float4*)&rowst[w][3][seg * 8 + 4];
            float x0 = p[(size_t)(seg * 8 + 0) * NN];
            float x1 = p[(size_t)(seg * 8 + 1) * NN];
            float x2 = p[(size_t)(seg * 8 + 2) * NN];
            float x3 = p[(size_t)(seg * 8 + 3) * NN];
            float x4 = p[(size_t)(seg * 8 + 4) * NN];
            float x5 = p[(size_t)(seg * 8 + 5) * NN];
            float x6 = p[(size_t)(seg * 8 + 6) * NN];
            float x7 = p[(size_t)(seg * 8 + 7) * NN];
            // ascending-c chain per row (frozen order)
            a0 = fmaf(ra0.x, x0, a0); a0 = fmaf(ra0.y, x1, a0);
            a0 = fmaf(ra0.z, x2, a0); a0 = fmaf(ra0.w, x3, a0);
            a0 = fmaf(rb0.x, x4, a0); a0 = fmaf(rb0.y, x5, a0);
            a0 = fmaf(rb0.z, x6, a0); a0 = fmaf(rb0.w, x7, a0);
            a1 = fmaf(ra1.x, x0, a1); a1 = fmaf(ra1.y, x1, a1);
            a1 = fmaf(ra1.z, x2, a1); a1 = fmaf(ra1.w, x3, a1);
            a1 = fmaf(rb1.x, x4, a1); a1 = fmaf(rb1.y, x5, a1);
            a1 = fmaf(rb1.z, x6, a1); a1 = fmaf(rb1.w, x7, a1);
            a2 = fmaf(ra2.x, x0, a2); a2 = fmaf(ra2.y, x1, a2);
            a2 = fmaf(ra2.z, x2, a2); a2 = fmaf(ra2.w, x3, a2);
            a2 = fmaf(rb2.x, x4, a2); a2 = fmaf(rb2.y, x5, a2);
            a2 = fmaf(rb2.z, x6, a2); a2 = fmaf(rb2.w, x7, a2);
            a3 = fmaf(ra3.x, x0, a3); a3 = fmaf(ra3.y, x1, a3);
            a3 = fmaf(ra3.z, x2, a3); a3 = fmaf(ra3.w, x3, a3);
            a3 = fmaf(rb3.x, x4, a3); a3 = fmaf(rb3.y, x5, a3);
            a3 = fmaf(rb3.z, x6, a3); a3 = fmaf(rb3.w, x7, a3);
        }
        // frozen epilogue + stable insert (no-op when nd <= current t[7])
        {
            float inner = __fmul_rn(-2.f, a0);
            float t1v = __fsub_rn(-nbv, inner);
            float nd = __fsub_rn(t1v, xxi[0]);
            if (nd > tl[0][7]) ins8(nd, col, tl[0], il[0]);
        }
        {
            float inner = __fmul_rn(-2.f, a1);
            float t1v = __fsub_rn(-nbv, inner);
            float nd = __fsub_rn(t1v, xxi[1]);
            if (nd > tl[1][7]) ins8(nd, col, tl[1], il[1]);
        }
        {
            float inner = __fmul_rn(-2.f, a2);
            float t1v = __fsub_rn(-nbv, inner);
            float nd = __fsub_rn(t1v, xxi[2]);
            if (nd > tl[2][7]) ins8(nd, col, tl[2], il[2]);
        }
        {
            float inner = __fmul_rn(-2.f, a3);
            float t1v = __fsub_rn(-nbv, inner);
            float nd = __fsub_rn(t1v, xxi[3]);
            if (nd > tl[3][7]) ins8(nd, col, tl[3], il[3]);
        }
    }

    // extraction: 20 stable global maxima per row
    #pragma unroll
    for (int j = 0; j < 4; ++j) {
        unsigned mask = 0;
        int myout = 0;
        #pragma unroll 1
        for (int it = 0; it < 20; ++it) {
            if (__ballot(tl[j][0] == NEG_INF)) {      // rare exhaustion
                if (tl[j][0] == NEG_INF)
                    rebuild_row(doutc, nrmb, &rowst[w][j][0], xxi[j], mask,
                                lane, tl[j], il[j]);
            }
            float wv = tl[j][0];
            #pragma unroll
            for (int d = 32; d; d >>= 1) wv = fmaxf(wv, __shfl_xor(wv, d));
            int cand = (tl[j][0] == wv) ? il[j][0] : 0x7fffffff;
            #pragma unroll
            for (int d = 32; d; d >>= 1) cand = min(cand, __shfl_xor(cand, d));
            if (lane == it) myout = cand;
            if (tl[j][0] == wv && il[j][0] == cand) { // owner pops front
                mask |= 1u << (cand >> 6);
                #pragma unroll
                for (int q = 0; q < 7; ++q) {
                    tl[j][q] = tl[j][q + 1];
                    il[j][q] = il[j][q + 1];
                }
                tl[j][7] = NEG_INF; il[j][7] = 0x7fffffff;
            }
        }
        if (lane < 20)
            idx[((size_t)bb * NN + r0 + j) * KK + lane] = myout;
    }
}

// ---------------------------------------------------------------------------
// EdgeConv blocks, fp64 accumulate (LDS-staged weights/rows, hoisted ctr-half).
// ---------------------------------------------------------------------------
__global__ __launch_bounds__(256) void conv1_k(const float* __restrict__ x,
        const int* __restrict__ idxb, const float* __restrict__ wb,
        const float* __restrict__ b1, const float* __restrict__ b2,
        float* __restrict__ dout, float* __restrict__ x123t) {
    __shared__ float w2t_s[4096];
    __shared__ double h1b[4][64];
    int tid = threadIdx.x, lane = tid & 63, w = tid >> 6;
    for (int i = tid; i < 4096; i += 256) w2t_s[i] = wb[384 + i];
    __syncthreads();
    int p = blockIdx.x * 4 + w, b = p >> 11, n = p & 2047;
    const float* xb = x + (size_t)b * 3 * NN;
    double c0 = (double)xb[n], c1 = (double)xb[NN + n], c2 = (double)xb[2 * NN + n];
    double wl0 = (double)wb[0 * 64 + lane], wl1 = (double)wb[1 * 64 + lane],
           wl2 = (double)wb[2 * 64 + lane];
    double hc = (double)b1[lane];
    hc = fma((double)wb[192 + 0 * 64 + lane], c0, hc);
    hc = fma((double)wb[192 + 1 * 64 + lane], c1, hc);
    hc = fma((double)wb[192 + 2 * 64 + lane], c2, hc);
    double bb2 = (double)b2[lane];
    const int* ip = idxb + (size_t)p * KK;
    double m = DNEG;
    #pragma unroll 2
    for (int kk = 0; kk < KK; ++kk) {
        int nb = ip[kk];
        double h1 = hc;
        h1 = fma(wl0, (double)xb[nb] - c0, h1);
        h1 = fma(wl1, (double)xb[NN + nb] - c1, h1);
        h1 = fma(wl2, (double)xb[2 * NN + nb] - c2, h1);
        h1b[w][lane] = h1;
        double q0 = bb2, q1 = 0, q2 = 0, q3 = 0;
        #pragma unroll
        for (int j = 0; j < 64; j += 4) {
            q0 = fma((double)w2t_s[(j + 0) * 64 + lane], h1b[w][j + 0], q0);
            q1 = fma((double)w2t_s[(j + 1) * 64 + lane], h1b[w][j + 1], q1);
            q2 = fma((double)w2t_s[(j + 2) * 64 + lane], h1b[w][j + 2], q2);
            q3 = fma((double)w2t_s[(j + 3) * 64 + lane], h1b[w][j + 3], q3);
        }
        m = fmax(m, (q0 + q1) + (q2 + q3));
    }
    dout[((size_t)b * 192 + lane) * NN + n] = (float)m;
    x123t[((size_t)b * NN + n) * 192 + lane] = (float)m;
}

__global__ __launch_bounds__(256) void conv2_k(const float* __restrict__ x123t,
        const int* __restrict__ idxb, const float* __restrict__ wb,
        const float* __restrict__ b3, const float* __restrict__ b4,
        float* __restrict__ dout, float* __restrict__ x123t_o) {
    __shared__ float w3lo_s[4096], w4t_s[4096];
    __shared__ double cb[4][64], db[4][64], h1b[4][64];
    int tid = threadIdx.x, lane = tid & 63, w = tid >> 6;
    for (int i = tid; i < 4096; i += 256) {
        w3lo_s[i] = wb[4480 + i];
        w4t_s[i]  = wb[12672 + i];
    }
    __syncthreads();
    int p = blockIdx.x * 4 + w, b = p >> 11, n = p & 2047;
    const float* base = x123t + (size_t)b * NN * 192;
    double ctr = (double)base[(size_t)n * 192 + lane];
    cb[w][lane] = ctr;
    double h0 = (double)b3[lane], h1a = 0, h2a = 0, h3a = 0;
    #pragma unroll 4
    for (int c = 0; c < 64; c += 4) {
        h0  = fma((double)wb[8576 + (c + 0) * 64 + lane], cb[w][c + 0], h0);
        h1a = fma((double)wb[8576 + (c + 1) * 64 + lane], cb[w][c + 1], h1a);
        h2a = fma((double)wb[8576 + (c + 2) * 64 + lane], cb[w][c + 2], h2a);
        h3a = fma((double)wb[8576 + (c + 3) * 64 + lane], cb[w][c + 3], h3a);
    }
    double hc = (h0 + h1a) + (h2a + h3a);
    double bb4 = (double)b4[lane];
    const int* ip = idxb + (size_t)p * KK;
    double m = DNEG;
    #pragma unroll 1
    for (int kk = 0; kk < KK; ++kk) {
        int nb = ip[kk];
        db[w][lane] = (double)base[(size_t)nb * 192 + lane] - ctr;
        double a0 = hc, a1 = 0, a2 = 0, a3 = 0;
        #pragma unroll
        for (int c = 0; c < 64; c += 4) {
            a0 = fma((double)w3lo_s[(c + 0) * 64 + lane], db[w][c + 0], a0);
            a1 = fma((double)w3lo_s[(c + 1) * 64 + lane], db[w][c + 1], a1);
            a2 = fma((double)w3lo_s[(c + 2) * 64 + lane], db[w][c + 2], a2);
            a3 = fma((double)w3lo_s[(c + 3) * 64 + lane], db[w][c + 3], a3);
        }
        h1b[w][lane] = (a0 + a1) + (a2 + a3);
        double q0 = bb4, q1 = 0, q2 = 0, q3 = 0;
        #pragma unroll
        for (int j = 0; j < 64; j += 4) {
            q0 = fma((double)w4t_s[(j + 0) * 64 + lane], h1b[w][j + 0], q0);
            q1 = fma((double)w4t_s[(j + 1) * 64 + lane], h1b[w][j + 1], q1);
            q2 = fma((double)w4t_s[(j + 2) * 64 + lane], h1b[w][j + 2], q2);
            q3 = fma((double)w4t_s[(j + 3) * 64 + lane], h1b[w][j + 3], q3);
        }
        m = fmax(m, (q0 + q1) + (q2 + q3));
    }
    dout[((size_t)b * 192 + 64 + lane) * NN + n] = (float)m;
    x123t_o[((size_t)b * NN + n) * 192 + 64 + lane] = (float)m;
}

__global__ __launch_bounds__(256) void conv3_k(const float* __restrict__ x123t,
        const int* __restrict__ idxb, const float* __restrict__ wb,
        const float* __restrict__ b5,
        float* __restrict__ dout, float* __restrict__ x123t_o) {
    __shared__ float w5lo_s[4096];
    __shared__ double cb[4][64], db[4][64];
    int tid = threadIdx.x, lane = tid & 63, w = tid >> 6;
    for (int i = tid; i < 4096; i += 256) w5lo_s[i] = wb[16768 + i];
    __syncthreads();
    int p = blockIdx.x * 4 + w, b = p >> 11, n = p & 2047;
    const float* base = x123t + (size_t)b * NN * 192 + 64;  // x2 slice
    double ctr = (double)base[(size_t)n * 192 + lane];
    cb[w][lane] = ctr;
    double h0 = (double)b5[lane], h1a = 0, h2a = 0, h3a = 0;
    #pragma unroll 4
    for (int c = 0; c < 64; c += 4) {
        h0  = fma((double)wb[20864 + (c + 0) * 64 + lane], cb[w][c + 0], h0);
        h1a = fma((double)wb[20864 + (c + 1) * 64 + lane], cb[w][c + 1], h1a);
        h2a = fma((double)wb[20864 + (c + 2) * 64 + lane], cb[w][c + 2], h2a);
        h3a = fma((double)wb[20864 + (c + 3) * 64 + lane], cb[w][c + 3], h3a);
    }
    double hc = (h0 + h1a) + (h2a + h3a);
    const int* ip = idxb + (size_t)p * KK;
    double m = DNEG;
    #pragma unroll 1
    for (int kk = 0; kk < KK; ++kk) {
        int nb = ip[kk];
        db[w][lane] = (double)base[(size_t)nb * 192 + lane] - ctr;
        double a0 = hc, a1 = 0, a2 = 0, a3 = 0;
        #pragma unroll
        for (int c = 0; c < 64; c += 4) {
            a0 = fma((double)w5lo_s[(c + 0) * 64 + lane], db[w][c + 0], a0);
            a1 = fma((double)w5lo_s[(c + 1) * 64 + lane], db[w][c + 1], a1);
            a2 = fma((double)w5lo_s[(c + 2) * 64 + lane], db[w][c + 2], a2);
            a3 = fma((double)w5lo_s[(c + 3) * 64 + lane], db[w][c + 3], a3);
        }
        m = fmax(m, (a0 + a1) + (a2 + a3));
    }
    dout[((size_t)b * 192 + 128 + lane) * NN + n] = (float)m;
    x123t_o[((size_t)b * NN + n) * 192 + 128 + lane] = (float)m;
}

// ---------------------------------------------------------------------------
// Final conv1d (1024x192) as LDS-tiled f32 GEMM, 64o x 64n per block, KC=32.
// ---------------------------------------------------------------------------
#define KC 32
__global__ __launch_bounds__(256) void w6_k(const float* __restrict__ x123t,
                                            const float* __restrict__ w6,
                                            float* __restrict__ partial6) {
    __shared__ float xs[KC][68];
    __shared__ float wsb[KC][68];
    __shared__ float red[64][17];
    int tid = threadIdx.x;
    int ntile = blockIdx.x & 31, ot = (blockIdx.x >> 5) & 15, b = blockIdx.x >> 9;
    int n0 = ntile * 64, o0 = ot * 64;
    int ln = tid >> 2, lc = (tid & 3) * 8;
    const float* xrow = x123t + ((size_t)b * NN + n0 + ln) * 192 + lc;
    const float* wrow = w6 + (size_t)(o0 + ln) * 192 + lc;
    float acc[4][4];
    #pragma unroll
    for (int i = 0; i < 4; ++i)
        #pragma unroll
        for (int j = 0; j < 4; ++j) acc[i][j] = 0.f;
    int to = tid & 15, tn = tid >> 4;
    for (int cc = 0; cc < 192; cc += KC) {
        float4 xa = *(const float4*)(xrow + cc);
        float4 xb4 = *(const float4*)(xrow + cc + 4);
        float4 wa = *(const float4*)(wrow + cc);
        float4 wb4 = *(const float4*)(wrow + cc + 4);
        __syncthreads();
        xs[lc + 0][ln] = xa.x; xs[lc + 1][ln] = xa.y;
        xs[lc + 2][ln] = xa.z; xs[lc + 3][ln] = xa.w;
        xs[lc + 4][ln] = xb4.x; xs[lc + 5][ln] = xb4.y;
        xs[lc + 6][ln] = xb4.z; xs[lc + 7][ln] = xb4.w;
        wsb[lc + 0][ln] = wa.x; wsb[lc + 1][ln] = wa.y;
        wsb[lc + 2][ln] = wa.z; wsb[lc + 3][ln] = wa.w;
        wsb[lc + 4][ln] = wb4.x; wsb[lc + 5][ln] = wb4.y;
        wsb[lc + 6][ln] = wb4.z; wsb[lc + 7][ln] = wb4.w;
        __syncthreads();
        #pragma unroll
        for (int k = 0; k < KC; ++k) {
            float4 wv = *(const float4*)&wsb[k][to * 4];
            float4 xv = *(const float4*)&xs[k][tn * 4];
            float wr[4] = {wv.x, wv.y, wv.z, wv.w};
            float xr[4] = {xv.x, xv.y, xv.z, xv.w};
            #pragma unroll
            for (int i = 0; i < 4; ++i)
                #pragma unroll
                for (int j = 0; j < 4; ++j)
                    acc[i][j] = fmaf(wr[i], xr[j], acc[i][j]);
        }
    }
    #pragma unroll
    for (int i = 0; i < 4; ++i) {
        float mm = fmaxf(fmaxf(acc[i][0], acc[i][1]), fmaxf(acc[i][2], acc[i][3]));
        red[to * 4 + i][tn] = mm;
    }
    __syncthreads();
    if (tid < 64) {
        float mm = red[tid][0];
        #pragma unroll
        for (int t = 1; t < 16; ++t) mm = fmaxf(mm, red[tid][t]);
        partial6[((size_t)b * 1024 + o0 + tid) * 32 + ntile] = mm;
    }
}

__global__ void final_k(const float* __restrict__ partial6, const float* __restrict__ b6,
                        float* __restrict__ dout) {
    int t = blockIdx.x * 256 + threadIdx.x;  // < 16*1024
    int o = t & 1023;
    float m = NEG_INF;
    #pragma unroll 1
    for (int nt = 0; nt < 32; ++nt) m = fmaxf(m, partial6[(size_t)t * 32 + nt]);
    dout[(size_t)BB * 192 * NN + t] = m + b6[o];
}

// ---------------------------------------------------------------------------
extern "C" void kernel_launch(void* const* d_in, const int* in_sizes, int n_in,
                              void* d_out_, int out_size, void* d_ws, size_t ws_size,
                              hipStream_t stream) {
    (void)in_sizes; (void)n_in; (void)out_size; (void)ws_size;
    const float* x  = (const float*)d_in[0];
    const float* w1 = (const float*)d_in[1];
    const float* b1 = (const float*)d_in[2];
    const float* w2 = (const float*)d_in[3];
    const float* b2 = (const float*)d_in[4];
    const float* w3 = (const float*)d_in[5];
    const float* b3 = (const float*)d_in[6];
    const float* w4 = (const float*)d_in[7];
    const float* b4 = (const float*)d_in[8];
    const float* w5 = (const float*)d_in[9];
    const float* b5 = (const float*)d_in[10];
    const float* w6 = (const float*)d_in[11];
    const float* b6 = (const float*)d_in[12];
    float* dout = (float*)d_out_;

    char* ws = (char*)d_ws;
    float* x123t    = (float*)(ws + 0);           // 25,165,824 B
    int*   idxb     = (int*)(ws + 25165824);      //  2,621,440 B
    float* wbuf     = (float*)(ws + 27787264);    //     99,840 B
    float* nrm      = (float*)(ws + 27887104);    //    131,072 B
    float* partial6 = (float*)(ws + 28018176);    //  2,097,152 B

    prep_wf<<<1, 256, 0, stream>>>(w1, w2, w3, w4, w5, wbuf);

    // ---- block 1 ----
    knn1_k<<<dim3(1024, BB), 128, 0, stream>>>(x, idxb);
    conv1_k<<<8192, 256, 0, stream>>>(x, idxb, wbuf, b1, b2, dout, x123t);

    // ---- block 2 ----
    norms23_k<<<128, 256, 0, stream>>>(x123t, 0, nrm);
    knn23g_k<<<dim3(128, BB), 256, 0, stream>>>(x123t, dout, 0, nrm, idxb);
    conv2_k<<<8192, 256, 0, stream>>>(x123t, idxb, wbuf, b3, b4, dout, x123t);

    // ---- block 3 ----
    norms23_k<<<128, 256, 0, stream>>>(x123t, 64, nrm);
    knn23g_k<<<dim3(128, BB), 256, 0, stream>>>(x123t, dout, 64, nrm, idxb);
    conv3_k<<<8192, 256, 0, stream>>>(x123t, idxb, wbuf, b5, dout, x123t);

    // ---- final conv1d + global max ----
    w6_k<<<8192, 256, 0, stream>>>(x123t, w6, partial6);
    final_k<<<64, 256, 0, stream>>>(partial6, b6, dout);
}

// Round 10
// 4164.620 us; speedup vs baseline: 5.1478x; 1.4132x over previous
//
#include <hip/hip_runtime.h>

// Problem constants
#define BB 16
#define NN 2048
#define KK 20

#define NEG_INF (-3.402823466e+38f)
#define DNEG (-1.0e300)

// ---------------------------------------------------------------------------
// Weight prep: transposed f32 copies (exact). Float offsets in wb:
//   w1tlo[3][64]@0  w1thi[3][64]@192  w2t[64][64]@384
//   w3lo[64][64]@4480  w3hi[64][64]@8576  w4t[64][64]@12672
//   w5lo[64][64]@16768 w5hi[64][64]@20864      (total 24960 floats)
// ---------------------------------------------------------------------------
__global__ void prep_wf(const float* __restrict__ w1, const float* __restrict__ w2,
                        const float* __restrict__ w3, const float* __restrict__ w4,
                        const float* __restrict__ w5, float* __restrict__ wb) {
    int t = threadIdx.x;
    for (int i = t; i < 192; i += 256) {
        int c = i >> 6, j = i & 63;
        wb[i]       = w1[j * 6 + c];
        wb[192 + i] = w1[j * 6 + 3 + c];
    }
    for (int i = t; i < 4096; i += 256) {
        int a = i >> 6, q = i & 63;
        wb[384 + i]   = w2[q * 64 + a];        // w2t[j=a][o=q]
        wb[4480 + i]  = w3[q * 128 + a];       // w3lo[c=a][j=q]
        wb[8576 + i]  = w3[q * 128 + 64 + a];  // w3hi[c=a][j=q]
        wb[12672 + i] = w4[q * 64 + a];        // w4t[j=a][o=q]
        wb[16768 + i] = w5[q * 128 + a];       // w5lo[c=a][o=q]
        wb[20864 + i] = w5[q * 128 + 64 + a];  // w5hi[c=a][o=q]
    }
}

// ---------------------------------------------------------------------------
// Top-20 selection over 2048 f32 candidates in a per-wave LDS row (knn1 only).
// FROZEN (passing arithmetic): stable ties -> lowest index.
// ---------------------------------------------------------------------------
__device__ __forceinline__ void top2_upd(float v, int g, float& av, int& ai,
                                         float& bv, int& bi) {
    bool gta = v > av;
    bool gtb = v > bv;
    float nbv = gta ? av : (gtb ? v : bv);
    int   nbi = gta ? ai : (gtb ? g : bi);
    av = gta ? v : av;
    ai = gta ? g : ai;
    bv = nbv;
    bi = nbi;
}

__device__ __forceinline__ void topk20_run(float* vrow, int lane, float av, int ai,
                                           float bv, int bi, int* outp) {
    int myout = 0;
    #pragma unroll 1
    for (int it = 0; it < 20; ++it) {
        float wv = av;
        #pragma unroll
        for (int d = 32; d; d >>= 1) wv = fmaxf(wv, __shfl_xor(wv, d));
        unsigned long long bal = __ballot(av == wv);
        int widx;
        if (__popcll(bal) == 1) {
            widx = __shfl(ai, __ffsll(bal) - 1);
        } else {  // exact tie across lanes: lowest global index wins
            int tt = (av == wv) ? ai : 0x7fffffff;
            #pragma unroll
            for (int d = 32; d; d >>= 1) tt = min(tt, __shfl_xor(tt, d));
            widx = tt;
        }
        if (lane == it) myout = widx;
        if (lane == 0) vrow[widx] = NEG_INF;   // remove winner
        if (ai == widx) { av = bv; ai = bi; bv = NEG_INF; bi = 0x7fffffff; }
        if (av == NEG_INF) {                   // rare: lane's top-2 exhausted
            ai = 0x7fffffff; bv = NEG_INF; bi = 0x7fffffff;
            #pragma unroll 1
            for (int s = 0; s < 32; ++s) {
                int col = s * 64 + lane;
                top2_upd(vrow[col], col, av, ai, bv, bi);
            }
        }
    }
    if (lane < 20) outp[lane] = myout;
}

// ---------------------------------------------------------------------------
// knn1: numpy-f32 mirror of pd = -xx - (-2*(xt@x)) - xx.T on raw x (C=3).
// FROZEN arithmetic.
// ---------------------------------------------------------------------------
__global__ void knn1_k(const float* __restrict__ x, int* __restrict__ idx) {
    __shared__ float vlds[2][2048];
    int lane = threadIdx.x & 63, w = threadIdx.x >> 6;
    int b = blockIdx.y, r = blockIdx.x * 2 + w;
    const float* xb = x + (size_t)b * 3 * NN;
    float rx = xb[r], ry = xb[NN + r], rz = xb[2 * NN + r];
    float xxi = __fadd_rn(__fadd_rn(__fmul_rn(rx, rx), __fmul_rn(ry, ry)),
                          __fmul_rn(rz, rz));
    float* vrow = vlds[w];
    float av = NEG_INF, bv = NEG_INF;
    int ai = 0x7fffffff, bi = 0x7fffffff;
    #pragma unroll 1
    for (int s = 0; s < 32; ++s) {
        int col = s * 64 + lane;
        float cx = xb[col], cy = xb[NN + col], cz = xb[2 * NN + col];
        float xxj = __fadd_rn(__fadd_rn(__fmul_rn(cx, cx), __fmul_rn(cy, cy)),
                              __fmul_rn(cz, cz));
        float dot = fmaf(rz, cz, fmaf(ry, cy, __fmul_rn(rx, cx)));
        float inner = __fmul_rn(-2.f, dot);
        float t1 = __fsub_rn(-xxj, inner);
        float nd = __fsub_rn(t1, xxi);
        vrow[col] = nd;
        top2_upd(nd, col, av, ai, bv, bi);
    }
    topk20_run(vrow, lane, av, ai, bv, bi, idx + ((size_t)b * NN + r) * KK);
}

// xx for a 64-channel slice: squares rounded, sequential ascending-c sum. FROZEN.
__global__ void norms23_k(const float* __restrict__ x123t, int coff,
                          float* __restrict__ nrm) {
    int t = blockIdx.x * 256 + threadIdx.x;   // 32768 points
    const float* r = x123t + (size_t)t * 192 + coff;
    float acc = 0.f;
    #pragma unroll 1
    for (int c = 0; c < 64; ++c)
        acc = __fadd_rn(acc, __fmul_rn(r[c], r[c]));
    nrm[t] = acc;
}

// ---------------------------------------------------------------------------
// knn2/3: channel-major reads from dout slab. 2 rows/wave (occupancy fix).
// Frozen FMA chain per (row,col): ascending-c single-accumulator fmaf;
// frozen epilogue. Per-lane sorted top-8 lists, stable extraction,
// rare exhaustion -> exact recompute fallback (same chain).
// ---------------------------------------------------------------------------
__device__ __forceinline__ void ins8(float v, int g, float (&t)[8], int (&ix)[8]) {
    bool c0 = v > t[0], c1 = v > t[1], c2 = v > t[2], c3 = v > t[3];
    bool c4 = v > t[4], c5 = v > t[5], c6 = v > t[6], c7 = v > t[7];
    t[7] = c7 ? (c6 ? t[6] : v) : t[7];  ix[7] = c7 ? (c6 ? ix[6] : g) : ix[7];
    t[6] = c6 ? (c5 ? t[5] : v) : t[6];  ix[6] = c6 ? (c5 ? ix[5] : g) : ix[6];
    t[5] = c5 ? (c4 ? t[4] : v) : t[5];  ix[5] = c5 ? (c4 ? ix[4] : g) : ix[5];
    t[4] = c4 ? (c3 ? t[3] : v) : t[4];  ix[4] = c4 ? (c3 ? ix[3] : g) : ix[4];
    t[3] = c3 ? (c2 ? t[2] : v) : t[3];  ix[3] = c3 ? (c2 ? ix[2] : g) : ix[3];
    t[2] = c2 ? (c1 ? t[1] : v) : t[2];  ix[2] = c2 ? (c1 ? ix[1] : g) : ix[2];
    t[1] = c1 ? (c0 ? t[0] : v) : t[1];  ix[1] = c1 ? (c0 ? ix[0] : g) : ix[1];
    t[0] = c0 ? v : t[0];                ix[0] = c0 ? g : ix[0];
}

__device__ __forceinline__ void rebuild_row(const float* __restrict__ doutc,
        const float* __restrict__ nrmb, const float* rowp, float xxi,
        unsigned mask, int lane, float (&t)[8], int (&ix)[8]) {
    #pragma unroll
    for (int q = 0; q < 8; ++q) { t[q] = NEG_INF; ix[q] = 0x7fffffff; }
    #pragma unroll 1
    for (int s = 0; s < 32; ++s) {
        if ((mask >> s) & 1u) continue;
        int col = s * 64 + lane;
        float acc = 0.f;
        #pragma unroll 1
        for (int c = 0; c < 64; ++c)
            acc = fmaf(rowp[c], doutc[(size_t)c * NN + col], acc);
        float inner = __fmul_rn(-2.f, acc);
        float t1 = __fsub_rn(-nrmb[col], inner);
        float nd = __fsub_rn(t1, xxi);
        ins8(nd, col, t, ix);
    }
}

__global__ __launch_bounds__(256) void knn23g_k(const float* __restrict__ x123t,
        const float* __restrict__ dout, int coff, const float* __restrict__ nrm,
        int* __restrict__ idx) {
    __shared__ float rowst[4][2][64];
    int lane = threadIdx.x & 63, w = threadIdx.x >> 6;
    int bb = blockIdx.y;
    int r0 = blockIdx.x * 8 + w * 2;
    const float* doutc = dout + (size_t)(bb * 192 + coff) * NN;
    const float* nrmb = nrm + (size_t)bb * NN;
    float xxi[2];
    #pragma unroll
    for (int j = 0; j < 2; ++j) {
        rowst[w][j][lane] = x123t[((size_t)bb * NN + r0 + j) * 192 + coff + lane];
        xxi[j] = nrmb[r0 + j];
    }
    float tl[2][8];
    int   il[2][8];
    #pragma unroll
    for (int j = 0; j < 2; ++j)
        #pragma unroll
        for (int q = 0; q < 8; ++q) { tl[j][q] = NEG_INF; il[j][q] = 0x7fffffff; }

    #pragma unroll 1
    for (int g = 0; g < 32; ++g) {
        int col = g * 64 + lane;
        float nbv = nrmb[col];
        float a0 = 0.f, a1 = 0.f;
        const float* p = doutc + col;
        #pragma unroll
        for (int seg = 0; seg < 8; ++seg) {
            float4 ra0 = *(const float4*)&rowst[w][0][seg * 8];
            float4 rb0 = *(const float4*)&rowst[w][0][seg * 8 + 4];
            float4 ra1 = *(const float4*)&rowst[w][1][seg * 8];
            float4 rb1 = *(const float4*)&rowst[w][1][seg * 8 + 4];
            float x0 = p[(size_t)(seg * 8 + 0) * NN];
            float x1 = p[(size_t)(seg * 8 + 1) * NN];
            float x2 = p[(size_t)(seg * 8 + 2) * NN];
            float x3 = p[(size_t)(seg * 8 + 3) * NN];
            float x4 = p[(size_t)(seg * 8 + 4) * NN];
            float x5 = p[(size_t)(seg * 8 + 5) * NN];
            float x6 = p[(size_t)(seg * 8 + 6) * NN];
            float x7 = p[(size_t)(seg * 8 + 7) * NN];
            // ascending-c chain per row (frozen order)
            a0 = fmaf(ra0.x, x0, a0); a0 = fmaf(ra0.y, x1, a0);
            a0 = fmaf(ra0.z, x2, a0); a0 = fmaf(ra0.w, x3, a0);
            a0 = fmaf(rb0.x, x4, a0); a0 = fmaf(rb0.y, x5, a0);
            a0 = fmaf(rb0.z, x6, a0); a0 = fmaf(rb0.w, x7, a0);
            a1 = fmaf(ra1.x, x0, a1); a1 = fmaf(ra1.y, x1, a1);
            a1 = fmaf(ra1.z, x2, a1); a1 = fmaf(ra1.w, x3, a1);
            a1 = fmaf(rb1.x, x4, a1); a1 = fmaf(rb1.y, x5, a1);
            a1 = fmaf(rb1.z, x6, a1); a1 = fmaf(rb1.w, x7, a1);
        }
        // frozen epilogue + stable insert (no-op when nd <= current t[7])
        {
            float inner = __fmul_rn(-2.f, a0);
            float t1v = __fsub_rn(-nbv, inner);
            float nd = __fsub_rn(t1v, xxi[0]);
            if (nd > tl[0][7]) ins8(nd, col, tl[0], il[0]);
        }
        {
            float inner = __fmul_rn(-2.f, a1);
            float t1v = __fsub_rn(-nbv, inner);
            float nd = __fsub_rn(t1v, xxi[1]);
            if (nd > tl[1][7]) ins8(nd, col, tl[1], il[1]);
        }
    }

    // extraction: 20 stable global maxima per row
    #pragma unroll
    for (int j = 0; j < 2; ++j) {
        unsigned mask = 0;
        int myout = 0;
        #pragma unroll 1
        for (int it = 0; it < 20; ++it) {
            if (__ballot(tl[j][0] == NEG_INF)) {      // rare exhaustion
                if (tl[j][0] == NEG_INF)
                    rebuild_row(doutc, nrmb, &rowst[w][j][0], xxi[j], mask,
                                lane, tl[j], il[j]);
            }
            float wv = tl[j][0];
            #pragma unroll
            for (int d = 32; d; d >>= 1) wv = fmaxf(wv, __shfl_xor(wv, d));
            int cand = (tl[j][0] == wv) ? il[j][0] : 0x7fffffff;
            #pragma unroll
            for (int d = 32; d; d >>= 1) cand = min(cand, __shfl_xor(cand, d));
            if (lane == it) myout = cand;
            if (tl[j][0] == wv && il[j][0] == cand) { // owner pops front
                mask |= 1u << (cand >> 6);
                #pragma unroll
                for (int q = 0; q < 7; ++q) {
                    tl[j][q] = tl[j][q + 1];
                    il[j][q] = il[j][q + 1];
                }
                tl[j][7] = NEG_INF; il[j][7] = 0x7fffffff;
            }
        }
        if (lane < 20)
            idx[((size_t)bb * NN + r0 + j) * KK + lane] = myout;
    }
}

// ---------------------------------------------------------------------------
// EdgeConv blocks, fp64 accumulate (LDS-staged weights/rows, hoisted ctr-half).
// ---------------------------------------------------------------------------
__global__ __launch_bounds__(256) void conv1_k(const float* __restrict__ x,
        const int* __restrict__ idxb, const float* __restrict__ wb,
        const float* __restrict__ b1, const float* __restrict__ b2,
        float* __restrict__ dout, float* __restrict__ x123t) {
    __shared__ float w2t_s[4096];
    __shared__ double h1b[4][64];
    int tid = threadIdx.x, lane = tid & 63, w = tid >> 6;
    for (int i = tid; i < 4096; i += 256) w2t_s[i] = wb[384 + i];
    __syncthreads();
    int p = blockIdx.x * 4 + w, b = p >> 11, n = p & 2047;
    const float* xb = x + (size_t)b * 3 * NN;
    double c0 = (double)xb[n], c1 = (double)xb[NN + n], c2 = (double)xb[2 * NN + n];
    double wl0 = (double)wb[0 * 64 + lane], wl1 = (double)wb[1 * 64 + lane],
           wl2 = (double)wb[2 * 64 + lane];
    double hc = (double)b1[lane];
    hc = fma((double)wb[192 + 0 * 64 + lane], c0, hc);
    hc = fma((double)wb[192 + 1 * 64 + lane], c1, hc);
    hc = fma((double)wb[192 + 2 * 64 + lane], c2, hc);
    double bb2 = (double)b2[lane];
    const int* ip = idxb + (size_t)p * KK;
    double m = DNEG;
    #pragma unroll 2
    for (int kk = 0; kk < KK; ++kk) {
        int nb = ip[kk];
        double h1 = hc;
        h1 = fma(wl0, (double)xb[nb] - c0, h1);
        h1 = fma(wl1, (double)xb[NN + nb] - c1, h1);
        h1 = fma(wl2, (double)xb[2 * NN + nb] - c2, h1);
        h1b[w][lane] = h1;
        double q0 = bb2, q1 = 0, q2 = 0, q3 = 0;
        #pragma unroll
        for (int j = 0; j < 64; j += 4) {
            q0 = fma((double)w2t_s[(j + 0) * 64 + lane], h1b[w][j + 0], q0);
            q1 = fma((double)w2t_s[(j + 1) * 64 + lane], h1b[w][j + 1], q1);
            q2 = fma((double)w2t_s[(j + 2) * 64 + lane], h1b[w][j + 2], q2);
            q3 = fma((double)w2t_s[(j + 3) * 64 + lane], h1b[w][j + 3], q3);
        }
        m = fmax(m, (q0 + q1) + (q2 + q3));
    }
    dout[((size_t)b * 192 + lane) * NN + n] = (float)m;
    x123t[((size_t)b * NN + n) * 192 + lane] = (float)m;
}

__global__ __launch_bounds__(256) void conv2_k(const float* __restrict__ x123t,
        const int* __restrict__ idxb, const float* __restrict__ wb,
        const float* __restrict__ b3, const float* __restrict__ b4,
        float* __restrict__ dout, float* __restrict__ x123t_o) {
    __shared__ float w3lo_s[4096], w4t_s[4096];
    __shared__ double cb[4][64], db[4][64], h1b[4][64];
    int tid = threadIdx.x, lane = tid & 63, w = tid >> 6;
    for (int i = tid; i < 4096; i += 256) {
        w3lo_s[i] = wb[4480 + i];
        w4t_s[i]  = wb[12672 + i];
    }
    __syncthreads();
    int p = blockIdx.x * 4 + w, b = p >> 11, n = p & 2047;
    const float* base = x123t + (size_t)b * NN * 192;
    double ctr = (double)base[(size_t)n * 192 + lane];
    cb[w][lane] = ctr;
    double h0 = (double)b3[lane], h1a = 0, h2a = 0, h3a = 0;
    #pragma unroll 4
    for (int c = 0; c < 64; c += 4) {
        h0  = fma((double)wb[8576 + (c + 0) * 64 + lane], cb[w][c + 0], h0);
        h1a = fma((double)wb[8576 + (c + 1) * 64 + lane], cb[w][c + 1], h1a);
        h2a = fma((double)wb[8576 + (c + 2) * 64 + lane], cb[w][c + 2], h2a);
        h3a = fma((double)wb[8576 + (c + 3) * 64 + lane], cb[w][c + 3], h3a);
    }
    double hc = (h0 + h1a) + (h2a + h3a);
    double bb4 = (double)b4[lane];
    const int* ip = idxb + (size_t)p * KK;
    double m = DNEG;
    #pragma unroll 1
    for (int kk = 0; kk < KK; ++kk) {
        int nb = ip[kk];
        db[w][lane] = (double)base[(size_t)nb * 192 + lane] - ctr;
        double a0 = hc, a1 = 0, a2 = 0, a3 = 0;
        #pragma unroll
        for (int c = 0; c < 64; c += 4) {
            a0 = fma((double)w3lo_s[(c + 0) * 64 + lane], db[w][c + 0], a0);
            a1 = fma((double)w3lo_s[(c + 1) * 64 + lane], db[w][c + 1], a1);
            a2 = fma((double)w3lo_s[(c + 2) * 64 + lane], db[w][c + 2], a2);
            a3 = fma((double)w3lo_s[(c + 3) * 64 + lane], db[w][c + 3], a3);
        }
        h1b[w][lane] = (a0 + a1) + (a2 + a3);
        double q0 = bb4, q1 = 0, q2 = 0, q3 = 0;
        #pragma unroll
        for (int j = 0; j < 64; j += 4) {
            q0 = fma((double)w4t_s[(j + 0) * 64 + lane], h1b[w][j + 0], q0);
            q1 = fma((double)w4t_s[(j + 1) * 64 + lane], h1b[w][j + 1], q1);
            q2 = fma((double)w4t_s[(j + 2) * 64 + lane], h1b[w][j + 2], q2);
            q3 = fma((double)w4t_s[(j + 3) * 64 + lane], h1b[w][j + 3], q3);
        }
        m = fmax(m, (q0 + q1) + (q2 + q3));
    }
    dout[((size_t)b * 192 + 64 + lane) * NN + n] = (float)m;
    x123t_o[((size_t)b * NN + n) * 192 + 64 + lane] = (float)m;
}

__global__ __launch_bounds__(256) void conv3_k(const float* __restrict__ x123t,
        const int* __restrict__ idxb, const float* __restrict__ wb,
        const float* __restrict__ b5,
        float* __restrict__ dout, float* __restrict__ x123t_o) {
    __shared__ float w5lo_s[4096];
    __shared__ double cb[4][64], db[4][64];
    int tid = threadIdx.x, lane = tid & 63, w = tid >> 6;
    for (int i = tid; i < 4096; i += 256) w5lo_s[i] = wb[16768 + i];
    __syncthreads();
    int p = blockIdx.x * 4 + w, b = p >> 11, n = p & 2047;
    const float* base = x123t + (size_t)b * NN * 192 + 64;  // x2 slice
    double ctr = (double)base[(size_t)n * 192 + lane];
    cb[w][lane] = ctr;
    double h0 = (double)b5[lane], h1a = 0, h2a = 0, h3a = 0;
    #pragma unroll 4
    for (int c = 0; c < 64; c += 4) {
        h0  = fma((double)wb[20864 + (c + 0) * 64 + lane], cb[w][c + 0], h0);
        h1a = fma((double)wb[20864 + (c + 1) * 64 + lane], cb[w][c + 1], h1a);
        h2a = fma((double)wb[20864 + (c + 2) * 64 + lane], cb[w][c + 2], h2a);
        h3a = fma((double)wb[20864 + (c + 3) * 64 + lane], cb[w][c + 3], h3a);
    }
    double hc = (h0 + h1a) + (h2a + h3a);
    const int* ip = idxb + (size_t)p * KK;
    double m = DNEG;
    #pragma unroll 1
    for (int kk = 0; kk < KK; ++kk) {
        int nb = ip[kk];
        db[w][lane] = (double)base[(size_t)nb * 192 + lane] - ctr;
        double a0 = hc, a1 = 0, a2 = 0, a3 = 0;
        #pragma unroll
        for (int c = 0; c < 64; c += 4) {
            a0 = fma((double)w5lo_s[(c + 0) * 64 + lane], db[w][c + 0], a0);
            a1 = fma((double)w5lo_s[(c + 1) * 64 + lane], db[w][c + 1], a1);
            a2 = fma((double)w5lo_s[(c + 2) * 64 + lane], db[w][c + 2], a2);
            a3 = fma((double)w5lo_s[(c + 3) * 64 + lane], db[w][c + 3], a3);
        }
        m = fmax(m, (a0 + a1) + (a2 + a3));
    }
    dout[((size_t)b * 192 + 128 + lane) * NN + n] = (float)m;
    x123t_o[((size_t)b * NN + n) * 192 + 128 + lane] = (float)m;
}

// ---------------------------------------------------------------------------
// Final conv1d (1024x192) as LDS-tiled f32 GEMM, 64o x 64n per block, KC=32.
// ---------------------------------------------------------------------------
#define KC 32
__global__ __launch_bounds__(256) void w6_k(const float* __restrict__ x123t,
                                            const float* __restrict__ w6,
                                            float* __restrict__ partial6) {
    __shared__ float xs[KC][68];
    __shared__ float wsb[KC][68];
    __shared__ float red[64][17];
    int tid = threadIdx.x;
    int ntile = blockIdx.x & 31, ot = (blockIdx.x >> 5) & 15, b = blockIdx.x >> 9;
    int n0 = ntile * 64, o0 = ot * 64;
    int ln = tid >> 2, lc = (tid & 3) * 8;
    const float* xrow = x123t + ((size_t)b * NN + n0 + ln) * 192 + lc;
    const float* wrow = w6 + (size_t)(o0 + ln) * 192 + lc;
    float acc[4][4];
    #pragma unroll
    for (int i = 0; i < 4; ++i)
        #pragma unroll
        for (int j = 0; j < 4; ++j) acc[i][j] = 0.f;
    int to = tid & 15, tn = tid >> 4;
    for (int cc = 0; cc < 192; cc += KC) {
        float4 xa = *(const float4*)(xrow + cc);
        float4 xb4 = *(const float4*)(xrow + cc + 4);
        float4 wa = *(const float4*)(wrow + cc);
        float4 wb4 = *(const float4*)(wrow + cc + 4);
        __syncthreads();
        xs[lc + 0][ln] = xa.x; xs[lc + 1][ln] = xa.y;
        xs[lc + 2][ln] = xa.z; xs[lc + 3][ln] = xa.w;
        xs[lc + 4][ln] = xb4.x; xs[lc + 5][ln] = xb4.y;
        xs[lc + 6][ln] = xb4.z; xs[lc + 7][ln] = xb4.w;
        wsb[lc + 0][ln] = wa.x; wsb[lc + 1][ln] = wa.y;
        wsb[lc + 2][ln] = wa.z; wsb[lc + 3][ln] = wa.w;
        wsb[lc + 4][ln] = wb4.x; wsb[lc + 5][ln] = wb4.y;
        wsb[lc + 6][ln] = wb4.z; wsb[lc + 7][ln] = wb4.w;
        __syncthreads();
        #pragma unroll
        for (int k = 0; k < KC; ++k) {
            float4 wv = *(const float4*)&wsb[k][to * 4];
            float4 xv = *(const float4*)&xs[k][tn * 4];
            float wr[4] = {wv.x, wv.y, wv.z, wv.w};
            float xr[4] = {xv.x, xv.y, xv.z, xv.w};
            #pragma unroll
            for (int i = 0; i < 4; ++i)
                #pragma unroll
                for (int j = 0; j < 4; ++j)
                    acc[i][j] = fmaf(wr[i], xr[j], acc[i][j]);
        }
    }
    #pragma unroll
    for (int i = 0; i < 4; ++i) {
        float mm = fmaxf(fmaxf(acc[i][0], acc[i][1]), fmaxf(acc[i][2], acc[i][3]));
        red[to * 4 + i][tn] = mm;
    }
    __syncthreads();
    if (tid < 64) {
        float mm = red[tid][0];
        #pragma unroll
        for (int t = 1; t < 16; ++t) mm = fmaxf(mm, red[tid][t]);
        partial6[((size_t)b * 1024 + o0 + tid) * 32 + ntile] = mm;
    }
}

__global__ void final_k(const float* __restrict__ partial6, const float* __restrict__ b6,
                        float* __restrict__ dout) {
    int t = blockIdx.x * 256 + threadIdx.x;  // < 16*1024
    int o = t & 1023;
    float m = NEG_INF;
    #pragma unroll 1
    for (int nt = 0; nt < 32; ++nt) m = fmaxf(m, partial6[(size_t)t * 32 + nt]);
    dout[(size_t)BB * 192 * NN + t] = m + b6[o];
}

// ---------------------------------------------------------------------------
extern "C" void kernel_launch(void* const* d_in, const int* in_sizes, int n_in,
                              void* d_out_, int out_size, void* d_ws, size_t ws_size,
                              hipStream_t stream) {
    (void)in_sizes; (void)n_in; (void)out_size; (void)ws_size;
    const float* x  = (const float*)d_in[0];
    const float* w1 = (const float*)d_in[1];
    const float* b1 = (const float*)d_in[2];
    const float* w2 = (const float*)d_in[3];
    const float* b2 = (const float*)d_in[4];
    const float* w3 = (const float*)d_in[5];
    const float* b3 = (const float*)d_in[6];
    const float* w4 = (const float*)d_in[7];
    const float* b4 = (const float*)d_in[8];
    const float* w5 = (const float*)d_in[9];
    const float* b5 = (const float*)d_in[10];
    const float* w6 = (const float*)d_in[11];
    const float* b6 = (const float*)d_in[12];
    float* dout = (float*)d_out_;

    char* ws = (char*)d_ws;
    float* x123t    = (float*)(ws + 0);           // 25,165,824 B
    int*   idxb     = (int*)(ws + 25165824);      //  2,621,440 B
    float* wbuf     = (float*)(ws + 27787264);    //     99,840 B
    float* nrm      = (float*)(ws + 27887104);    //    131,072 B
    float* partial6 = (float*)(ws + 28018176);    //  2,097,152 B

    prep_wf<<<1, 256, 0, stream>>>(w1, w2, w3, w4, w5, wbuf);

    // ---- block 1 ----
    knn1_k<<<dim3(1024, BB), 128, 0, stream>>>(x, idxb);
    conv1_k<<<8192, 256, 0, stream>>>(x, idxb, wbuf, b1, b2, dout, x123t);

    // ---- block 2 ----
    norms23_k<<<128, 256, 0, stream>>>(x123t, 0, nrm);
    knn23g_k<<<dim3(256, BB), 256, 0, stream>>>(x123t, dout, 0, nrm, idxb);
    conv2_k<<<8192, 256, 0, stream>>>(x123t, idxb, wbuf, b3, b4, dout, x123t);

    // ---- block 3 ----
    norms23_k<<<128, 256, 0, stream>>>(x123t, 64, nrm);
    knn23g_k<<<dim3(256, BB), 256, 0, stream>>>(x123t, dout, 64, nrm, idxb);
    conv3_k<<<8192, 256, 0, stream>>>(x123t, idxb, wbuf, b5, dout, x123t);

    // ---- final conv1d + global max ----
    w6_k<<<8192, 256, 0, stream>>>(x123t, w6, partial6);
    final_k<<<64, 256, 0, stream>>>(partial6, b6, dout);
}

// Round 11
// 2524.943 us; speedup vs baseline: 8.4907x; 1.6494x over previous
//
#include <hip/hip_runtime.h>

// Problem constants
#define BB 16
#define NN 2048
#define KK 20

#define NEG_INF (-3.402823466e+38f)
#define DNEG (-1.0e300)

// ---------------------------------------------------------------------------
// Weight prep (f32 transposes, used by conv3): offsets in wb:
//   w5lo[64][64]@16768 w5hi[64][64]@20864  (other slots unused but kept)
// ---------------------------------------------------------------------------
__global__ void prep_wf(const float* __restrict__ w1, const float* __restrict__ w2,
                        const float* __restrict__ w3, const float* __restrict__ w4,
                        const float* __restrict__ w5, float* __restrict__ wb) {
    int t = threadIdx.x;
    for (int i = t; i < 4096; i += 256) {
        int a = i >> 6, q = i & 63;
        wb[16768 + i] = w5[q * 128 + a];       // w5lo[c=a][o=q]
        wb[20864 + i] = w5[q * 128 + 64 + a];  // w5hi[c=a][o=q]
    }
}

// ---------------------------------------------------------------------------
// Composed fp64 weights:
//  M1[3][64]@0  Mh1[3][64]@192  g01[64]@384
//  M2[64][64]@448  Mh2[64][64]@4544  g02[64]@8640     (8704 doubles)
//  M1[c][o] = sum_j w2[o][j] w1[j][c] ; Mh1 with w1[j][3+c]
//  M2[c][o] = sum_j w4[o][j] w3[j][c] ; Mh2 with w3[j][64+c]
// ---------------------------------------------------------------------------
__global__ void prep_cmp(const float* __restrict__ w1, const float* __restrict__ b1,
                         const float* __restrict__ w2, const float* __restrict__ b2,
                         const float* __restrict__ w3, const float* __restrict__ b3,
                         const float* __restrict__ w4, const float* __restrict__ b4,
                         double* __restrict__ wd2) {
    int t = threadIdx.x;
    for (int i = t; i < 192; i += 256) {
        int c = i >> 6, o = i & 63;
        double s = 0, sh = 0;
        for (int j = 0; j < 64; ++j) {
            double w2v = (double)w2[o * 64 + j];
            s  = fma(w2v, (double)w1[j * 6 + c], s);
            sh = fma(w2v, (double)w1[j * 6 + 3 + c], sh);
        }
        wd2[i] = s;
        wd2[192 + i] = sh;
    }
    for (int i = t; i < 64; i += 256) {
        double s = (double)b2[i];
        for (int j = 0; j < 64; ++j)
            s = fma((double)w2[i * 64 + j], (double)b1[j], s);
        wd2[384 + i] = s;
        double s2 = (double)b4[i];
        for (int j = 0; j < 64; ++j)
            s2 = fma((double)w4[i * 64 + j], (double)b3[j], s2);
        wd2[8640 + i] = s2;
    }
    for (int i = t; i < 4096; i += 256) {
        int c = i >> 6, o = i & 63;
        double s = 0, sh = 0;
        for (int j = 0; j < 64; ++j) {
            double w4v = (double)w4[o * 64 + j];
            s  = fma(w4v, (double)w3[j * 128 + c], s);
            sh = fma(w4v, (double)w3[j * 128 + 64 + c], sh);
        }
        wd2[448 + i] = s;    // M2[c][o]
        wd2[4544 + i] = sh;  // Mh2[c][o]
    }
}

// ---------------------------------------------------------------------------
// Top-20 selection over 2048 f32 candidates in a per-wave LDS row (knn1 only).
// FROZEN: stable ties -> lowest index.
// ---------------------------------------------------------------------------
__device__ __forceinline__ void top2_upd(float v, int g, float& av, int& ai,
                                         float& bv, int& bi) {
    bool gta = v > av;
    bool gtb = v > bv;
    float nbv = gta ? av : (gtb ? v : bv);
    int   nbi = gta ? ai : (gtb ? g : bi);
    av = gta ? v : av;
    ai = gta ? g : ai;
    bv = nbv;
    bi = nbi;
}

__device__ __forceinline__ void topk20_run(float* vrow, int lane, float av, int ai,
                                           float bv, int bi, int* outp) {
    int myout = 0;
    #pragma unroll 1
    for (int it = 0; it < 20; ++it) {
        float wv = av;
        #pragma unroll
        for (int d = 32; d; d >>= 1) wv = fmaxf(wv, __shfl_xor(wv, d));
        unsigned long long bal = __ballot(av == wv);
        int widx;
        if (__popcll(bal) == 1) {
            widx = __shfl(ai, __ffsll(bal) - 1);
        } else {  // exact tie across lanes: lowest global index wins
            int tt = (av == wv) ? ai : 0x7fffffff;
            #pragma unroll
            for (int d = 32; d; d >>= 1) tt = min(tt, __shfl_xor(tt, d));
            widx = tt;
        }
        if (lane == it) myout = widx;
        if (lane == 0) vrow[widx] = NEG_INF;   // remove winner
        if (ai == widx) { av = bv; ai = bi; bv = NEG_INF; bi = 0x7fffffff; }
        if (av == NEG_INF) {                   // rare: lane's top-2 exhausted
            ai = 0x7fffffff; bv = NEG_INF; bi = 0x7fffffff;
            #pragma unroll 1
            for (int s = 0; s < 32; ++s) {
                int col = s * 64 + lane;
                top2_upd(vrow[col], col, av, ai, bv, bi);
            }
        }
    }
    if (lane < 20) outp[lane] = myout;
}

// ---------------------------------------------------------------------------
// knn1: numpy-f32 mirror, FROZEN arithmetic.
// ---------------------------------------------------------------------------
__global__ void knn1_k(const float* __restrict__ x, int* __restrict__ idx) {
    __shared__ float vlds[2][2048];
    int lane = threadIdx.x & 63, w = threadIdx.x >> 6;
    int b = blockIdx.y, r = blockIdx.x * 2 + w;
    const float* xb = x + (size_t)b * 3 * NN;
    float rx = xb[r], ry = xb[NN + r], rz = xb[2 * NN + r];
    float xxi = __fadd_rn(__fadd_rn(__fmul_rn(rx, rx), __fmul_rn(ry, ry)),
                          __fmul_rn(rz, rz));
    float* vrow = vlds[w];
    float av = NEG_INF, bv = NEG_INF;
    int ai = 0x7fffffff, bi = 0x7fffffff;
    #pragma unroll 1
    for (int s = 0; s < 32; ++s) {
        int col = s * 64 + lane;
        float cx = xb[col], cy = xb[NN + col], cz = xb[2 * NN + col];
        float xxj = __fadd_rn(__fadd_rn(__fmul_rn(cx, cx), __fmul_rn(cy, cy)),
                              __fmul_rn(cz, cz));
        float dot = fmaf(rz, cz, fmaf(ry, cy, __fmul_rn(rx, cx)));
        float inner = __fmul_rn(-2.f, dot);
        float t1 = __fsub_rn(-xxj, inner);
        float nd = __fsub_rn(t1, xxi);
        vrow[col] = nd;
        top2_upd(nd, col, av, ai, bv, bi);
    }
    topk20_run(vrow, lane, av, ai, bv, bi, idx + ((size_t)b * NN + r) * KK);
}

// xx for a 64-channel slice. FROZEN.
__global__ void norms23_k(const float* __restrict__ x123t, int coff,
                          float* __restrict__ nrm) {
    int t = blockIdx.x * 256 + threadIdx.x;   // 32768 points
    const float* r = x123t + (size_t)t * 192 + coff;
    float acc = 0.f;
    #pragma unroll 1
    for (int c = 0; c < 64; ++c)
        acc = __fadd_rn(acc, __fmul_rn(r[c], r[c]));
    nrm[t] = acc;
}

// ---------------------------------------------------------------------------
// knn2/3: channel-major reads from dout slab, 2 rows/wave. FROZEN chain.
// ---------------------------------------------------------------------------
__device__ __forceinline__ void ins8(float v, int g, float (&t)[8], int (&ix)[8]) {
    bool c0 = v > t[0], c1 = v > t[1], c2 = v > t[2], c3 = v > t[3];
    bool c4 = v > t[4], c5 = v > t[5], c6 = v > t[6], c7 = v > t[7];
    t[7] = c7 ? (c6 ? t[6] : v) : t[7];  ix[7] = c7 ? (c6 ? ix[6] : g) : ix[7];
    t[6] = c6 ? (c5 ? t[5] : v) : t[6];  ix[6] = c6 ? (c5 ? ix[5] : g) : ix[6];
    t[5] = c5 ? (c4 ? t[4] : v) : t[5];  ix[5] = c5 ? (c4 ? ix[4] : g) : ix[5];
    t[4] = c4 ? (c3 ? t[3] : v) : t[4];  ix[4] = c4 ? (c3 ? ix[3] : g) : ix[4];
    t[3] = c3 ? (c2 ? t[2] : v) : t[3];  ix[3] = c3 ? (c2 ? ix[2] : g) : ix[3];
    t[2] = c2 ? (c1 ? t[1] : v) : t[2];  ix[2] = c2 ? (c1 ? ix[1] : g) : ix[2];
    t[1] = c1 ? (c0 ? t[0] : v) : t[1];  ix[1] = c1 ? (c0 ? ix[0] : g) : ix[1];
    t[0] = c0 ? v : t[0];                ix[0] = c0 ? g : ix[0];
}

__device__ __forceinline__ void rebuild_row(const float* __restrict__ doutc,
        const float* __restrict__ nrmb, const float* rowp, float xxi,
        unsigned mask, int lane, float (&t)[8], int (&ix)[8]) {
    #pragma unroll
    for (int q = 0; q < 8; ++q) { t[q] = NEG_INF; ix[q] = 0x7fffffff; }
    #pragma unroll 1
    for (int s = 0; s < 32; ++s) {
        if ((mask >> s) & 1u) continue;
        int col = s * 64 + lane;
        float acc = 0.f;
        #pragma unroll 1
        for (int c = 0; c < 64; ++c)
            acc = fmaf(rowp[c], doutc[(size_t)c * NN + col], acc);
        float inner = __fmul_rn(-2.f, acc);
        float t1 = __fsub_rn(-nrmb[col], inner);
        float nd = __fsub_rn(t1, xxi);
        ins8(nd, col, t, ix);
    }
}

__global__ __launch_bounds__(256) void knn23g_k(const float* __restrict__ x123t,
        const float* __restrict__ dout, int coff, const float* __restrict__ nrm,
        int* __restrict__ idx) {
    __shared__ float rowst[4][2][64];
    int lane = threadIdx.x & 63, w = threadIdx.x >> 6;
    int bb = blockIdx.y;
    int r0 = blockIdx.x * 8 + w * 2;
    const float* doutc = dout + (size_t)(bb * 192 + coff) * NN;
    const float* nrmb = nrm + (size_t)bb * NN;
    float xxi[2];
    #pragma unroll
    for (int j = 0; j < 2; ++j) {
        rowst[w][j][lane] = x123t[((size_t)bb * NN + r0 + j) * 192 + coff + lane];
        xxi[j] = nrmb[r0 + j];
    }
    float tl[2][8];
    int   il[2][8];
    #pragma unroll
    for (int j = 0; j < 2; ++j)
        #pragma unroll
        for (int q = 0; q < 8; ++q) { tl[j][q] = NEG_INF; il[j][q] = 0x7fffffff; }

    #pragma unroll 1
    for (int g = 0; g < 32; ++g) {
        int col = g * 64 + lane;
        float nbv = nrmb[col];
        float a0 = 0.f, a1 = 0.f;
        const float* p = doutc + col;
        #pragma unroll
        for (int seg = 0; seg < 8; ++seg) {
            float4 ra0 = *(const float4*)&rowst[w][0][seg * 8];
            float4 rb0 = *(const float4*)&rowst[w][0][seg * 8 + 4];
            float4 ra1 = *(const float4*)&rowst[w][1][seg * 8];
            float4 rb1 = *(const float4*)&rowst[w][1][seg * 8 + 4];
            float x0 = p[(size_t)(seg * 8 + 0) * NN];
            float x1 = p[(size_t)(seg * 8 + 1) * NN];
            float x2 = p[(size_t)(seg * 8 + 2) * NN];
            float x3 = p[(size_t)(seg * 8 + 3) * NN];
            float x4 = p[(size_t)(seg * 8 + 4) * NN];
            float x5 = p[(size_t)(seg * 8 + 5) * NN];
            float x6 = p[(size_t)(seg * 8 + 6) * NN];
            float x7 = p[(size_t)(seg * 8 + 7) * NN];
            a0 = fmaf(ra0.x, x0, a0); a0 = fmaf(ra0.y, x1, a0);
            a0 = fmaf(ra0.z, x2, a0); a0 = fmaf(ra0.w, x3, a0);
            a0 = fmaf(rb0.x, x4, a0); a0 = fmaf(rb0.y, x5, a0);
            a0 = fmaf(rb0.z, x6, a0); a0 = fmaf(rb0.w, x7, a0);
            a1 = fmaf(ra1.x, x0, a1); a1 = fmaf(ra1.y, x1, a1);
            a1 = fmaf(ra1.z, x2, a1); a1 = fmaf(ra1.w, x3, a1);
            a1 = fmaf(rb1.x, x4, a1); a1 = fmaf(rb1.y, x5, a1);
            a1 = fmaf(rb1.z, x6, a1); a1 = fmaf(rb1.w, x7, a1);
        }
        {
            float inner = __fmul_rn(-2.f, a0);
            float t1v = __fsub_rn(-nbv, inner);
            float nd = __fsub_rn(t1v, xxi[0]);
            if (nd > tl[0][7]) ins8(nd, col, tl[0], il[0]);
        }
        {
            float inner = __fmul_rn(-2.f, a1);
            float t1v = __fsub_rn(-nbv, inner);
            float nd = __fsub_rn(t1v, xxi[1]);
            if (nd > tl[1][7]) ins8(nd, col, tl[1], il[1]);
        }
    }

    #pragma unroll
    for (int j = 0; j < 2; ++j) {
        unsigned mask = 0;
        int myout = 0;
        #pragma unroll 1
        for (int it = 0; it < 20; ++it) {
            if (__ballot(tl[j][0] == NEG_INF)) {      // rare exhaustion
                if (tl[j][0] == NEG_INF)
                    rebuild_row(doutc, nrmb, &rowst[w][j][0], xxi[j], mask,
                                lane, tl[j], il[j]);
            }
            float wv = tl[j][0];
            #pragma unroll
            for (int d = 32; d; d >>= 1) wv = fmaxf(wv, __shfl_xor(wv, d));
            int cand = (tl[j][0] == wv) ? il[j][0] : 0x7fffffff;
            #pragma unroll
            for (int d = 32; d; d >>= 1) cand = min(cand, __shfl_xor(cand, d));
            if (lane == it) myout = cand;
            if (tl[j][0] == wv && il[j][0] == cand) { // owner pops front
                mask |= 1u << (cand >> 6);
                #pragma unroll
                for (int q = 0; q < 7; ++q) {
                    tl[j][q] = tl[j][q + 1];
                    il[j][q] = il[j][q + 1];
                }
                tl[j][7] = NEG_INF; il[j][7] = 0x7fffffff;
            }
        }
        if (lane < 20)
            idx[((size_t)bb * NN + r0 + j) * KK + lane] = myout;
    }
}

// ---------------------------------------------------------------------------
// EdgeConv blocks with composed fp64 weights + neighbor prefetch.
// ---------------------------------------------------------------------------
__global__ __launch_bounds__(256) void conv1_k(const float* __restrict__ x,
        const int* __restrict__ idxb, const double* __restrict__ wd2,
        float* __restrict__ dout, float* __restrict__ x123t) {
    int tid = threadIdx.x, lane = tid & 63, w = tid >> 6;
    int p = blockIdx.x * 4 + w, b = p >> 11, n = p & 2047;
    const float* xb = x + (size_t)b * 3 * NN;
    double c0 = (double)xb[n], c1 = (double)xb[NN + n], c2 = (double)xb[2 * NN + n];
    double m10 = wd2[lane], m11 = wd2[64 + lane], m12 = wd2[128 + lane];
    double g = wd2[384 + lane];
    g = fma(wd2[192 + lane], c0, g);
    g = fma(wd2[256 + lane], c1, g);
    g = fma(wd2[320 + lane], c2, g);
    const int* ip = idxb + (size_t)p * KK;
    int nb = ip[0];
    float f0 = xb[nb], f1 = xb[NN + nb], f2 = xb[2 * NN + nb];
    double m = DNEG;
    #pragma unroll 1
    for (int kk = 0; kk < KK; ++kk) {
        double d0 = (double)f0 - c0, d1 = (double)f1 - c1, d2 = (double)f2 - c2;
        if (kk < KK - 1) {
            int nb2 = ip[kk + 1];
            f0 = xb[nb2]; f1 = xb[NN + nb2]; f2 = xb[2 * NN + nb2];
        }
        double h = g;
        h = fma(m10, d0, h);
        h = fma(m11, d1, h);
        h = fma(m12, d2, h);
        m = fmax(m, h);
    }
    dout[((size_t)b * 192 + lane) * NN + n] = (float)m;
    x123t[((size_t)b * NN + n) * 192 + lane] = (float)m;
}

__global__ __launch_bounds__(256) void conv2_k(const float* __restrict__ x123t,
        const int* __restrict__ idxb, const double* __restrict__ wd2,
        float* __restrict__ dout, float* __restrict__ x123t_o) {
    __shared__ double M2s[4096];   // 32 KB
    __shared__ double dbs[4][64];  // 2 KB
    int tid = threadIdx.x, lane = tid & 63, w = tid >> 6;
    for (int i = tid; i < 4096; i += 256) M2s[i] = wd2[448 + i];
    __syncthreads();
    int p = blockIdx.x * 4 + w, b = p >> 11, n = p & 2047;
    const float* base = x123t + (size_t)b * NN * 192;
    double ctr = (double)base[(size_t)n * 192 + lane];
    dbs[w][lane] = ctr;
    double g = wd2[8640 + lane];
    #pragma unroll 4
    for (int c = 0; c < 64; ++c)
        g = fma(wd2[4544 + c * 64 + lane], dbs[w][c], g);
    const int* ip = idxb + (size_t)p * KK;
    int nb = ip[0];
    float nbreg = base[(size_t)nb * 192 + lane];
    double m = DNEG;
    #pragma unroll 1
    for (int kk = 0; kk < KK; ++kk) {
        dbs[w][lane] = (double)nbreg - ctr;
        if (kk < KK - 1) {
            int nb2 = ip[kk + 1];
            nbreg = base[(size_t)nb2 * 192 + lane];
        }
        double a0 = g, a1 = 0, a2 = 0, a3 = 0;
        #pragma unroll
        for (int c = 0; c < 64; c += 4) {
            a0 = fma(M2s[(c + 0) * 64 + lane], dbs[w][c + 0], a0);
            a1 = fma(M2s[(c + 1) * 64 + lane], dbs[w][c + 1], a1);
            a2 = fma(M2s[(c + 2) * 64 + lane], dbs[w][c + 2], a2);
            a3 = fma(M2s[(c + 3) * 64 + lane], dbs[w][c + 3], a3);
        }
        m = fmax(m, (a0 + a1) + (a2 + a3));
    }
    dout[((size_t)b * 192 + 64 + lane) * NN + n] = (float)m;
    x123t_o[((size_t)b * NN + n) * 192 + 64 + lane] = (float)m;
}

__global__ __launch_bounds__(256) void conv3_k(const float* __restrict__ x123t,
        const int* __restrict__ idxb, const float* __restrict__ wb,
        const float* __restrict__ b5,
        float* __restrict__ dout, float* __restrict__ x123t_o) {
    __shared__ float w5s[4096];    // 16 KB
    __shared__ double dbs[4][64];  // 2 KB
    int tid = threadIdx.x, lane = tid & 63, w = tid >> 6;
    for (int i = tid; i < 4096; i += 256) w5s[i] = wb[16768 + i];
    __syncthreads();
    int p = blockIdx.x * 4 + w, b = p >> 11, n = p & 2047;
    const float* base = x123t + (size_t)b * NN * 192 + 64;  // x2 slice
    double ctr = (double)base[(size_t)n * 192 + lane];
    dbs[w][lane] = ctr;
    double h0 = (double)b5[lane], h1a = 0, h2a = 0, h3a = 0;
    #pragma unroll 4
    for (int c = 0; c < 64; c += 4) {
        h0  = fma((double)wb[20864 + (c + 0) * 64 + lane], dbs[w][c + 0], h0);
        h1a = fma((double)wb[20864 + (c + 1) * 64 + lane], dbs[w][c + 1], h1a);
        h2a = fma((double)wb[20864 + (c + 2) * 64 + lane], dbs[w][c + 2], h2a);
        h3a = fma((double)wb[20864 + (c + 3) * 64 + lane], dbs[w][c + 3], h3a);
    }
    double hc = (h0 + h1a) + (h2a + h3a);
    const int* ip = idxb + (size_t)p * KK;
    int nb = ip[0];
    float nbreg = base[(size_t)nb * 192 + lane];
    double m = DNEG;
    #pragma unroll 1
    for (int kk = 0; kk < KK; ++kk) {
        dbs[w][lane] = (double)nbreg - ctr;
        if (kk < KK - 1) {
            int nb2 = ip[kk + 1];
            nbreg = base[(size_t)nb2 * 192 + lane];
        }
        double a0 = hc, a1 = 0, a2 = 0, a3 = 0;
        #pragma unroll
        for (int c = 0; c < 64; c += 4) {
            a0 = fma((double)w5s[(c + 0) * 64 + lane], dbs[w][c + 0], a0);
            a1 = fma((double)w5s[(c + 1) * 64 + lane], dbs[w][c + 1], a1);
            a2 = fma((double)w5s[(c + 2) * 64 + lane], dbs[w][c + 2], a2);
            a3 = fma((double)w5s[(c + 3) * 64 + lane], dbs[w][c + 3], a3);
        }
        m = fmax(m, (a0 + a1) + (a2 + a3));
    }
    dout[((size_t)b * 192 + 128 + lane) * NN + n] = (float)m;
    x123t_o[((size_t)b * NN + n) * 192 + 128 + lane] = (float)m;
}

// ---------------------------------------------------------------------------
// Final conv1d (1024x192) as LDS-tiled f32 GEMM, 64o x 64n per block, KC=32.
// ---------------------------------------------------------------------------
#define KC 32
__global__ __launch_bounds__(256) void w6_k(const float* __restrict__ x123t,
                                            const float* __restrict__ w6,
                                            float* __restrict__ partial6) {
    __shared__ float xs[KC][68];
    __shared__ float wsb[KC][68];
    __shared__ float red[64][17];
    int tid = threadIdx.x;
    int ntile = blockIdx.x & 31, ot = (blockIdx.x >> 5) & 15, b = blockIdx.x >> 9;
    int n0 = ntile * 64, o0 = ot * 64;
    int ln = tid >> 2, lc = (tid & 3) * 8;
    const float* xrow = x123t + ((size_t)b * NN + n0 + ln) * 192 + lc;
    const float* wrow = w6 + (size_t)(o0 + ln) * 192 + lc;
    float acc[4][4];
    #pragma unroll
    for (int i = 0; i < 4; ++i)
        #pragma unroll
        for (int j = 0; j < 4; ++j) acc[i][j] = 0.f;
    int to = tid & 15, tn = tid >> 4;
    for (int cc = 0; cc < 192; cc += KC) {
        float4 xa = *(const float4*)(xrow + cc);
        float4 xb4 = *(const float4*)(xrow + cc + 4);
        float4 wa = *(const float4*)(wrow + cc);
        float4 wb4 = *(const float4*)(wrow + cc + 4);
        __syncthreads();
        xs[lc + 0][ln] = xa.x; xs[lc + 1][ln] = xa.y;
        xs[lc + 2][ln] = xa.z; xs[lc + 3][ln] = xa.w;
        xs[lc + 4][ln] = xb4.x; xs[lc + 5][ln] = xb4.y;
        xs[lc + 6][ln] = xb4.z; xs[lc + 7][ln] = xb4.w;
        wsb[lc + 0][ln] = wa.x; wsb[lc + 1][ln] = wa.y;
        wsb[lc + 2][ln] = wa.z; wsb[lc + 3][ln] = wa.w;
        wsb[lc + 4][ln] = wb4.x; wsb[lc + 5][ln] = wb4.y;
        wsb[lc + 6][ln] = wb4.z; wsb[lc + 7][ln] = wb4.w;
        __syncthreads();
        #pragma unroll
        for (int k = 0; k < KC; ++k) {
            float4 wv = *(const float4*)&wsb[k][to * 4];
            float4 xv = *(const float4*)&xs[k][tn * 4];
            float wr[4] = {wv.x, wv.y, wv.z, wv.w};
            float xr[4] = {xv.x, xv.y, xv.z, xv.w};
            #pragma unroll
            for (int i = 0; i < 4; ++i)
                #pragma unroll
                for (int j = 0; j < 4; ++j)
                    acc[i][j] = fmaf(wr[i], xr[j], acc[i][j]);
        }
    }
    #pragma unroll
    for (int i = 0; i < 4; ++i) {
        float mm = fmaxf(fmaxf(acc[i][0], acc[i][1]), fmaxf(acc[i][2], acc[i][3]));
        red[to * 4 + i][tn] = mm;
    }
    __syncthreads();
    if (tid < 64) {
        float mm = red[tid][0];
        #pragma unroll
        for (int t = 1; t < 16; ++t) mm = fmaxf(mm, red[tid][t]);
        partial6[((size_t)b * 1024 + o0 + tid) * 32 + ntile] = mm;
    }
}

__global__ void final_k(const float* __restrict__ partial6, const float* __restrict__ b6,
                        float* __restrict__ dout) {
    int t = blockIdx.x * 256 + threadIdx.x;  // < 16*1024
    int o = t & 1023;
    float m = NEG_INF;
    #pragma unroll 1
    for (int nt = 0; nt < 32; ++nt) m = fmaxf(m, partial6[(size_t)t * 32 + nt]);
    dout[(size_t)BB * 192 * NN + t] = m + b6[o];
}

// ---------------------------------------------------------------------------
extern "C" void kernel_launch(void* const* d_in, const int* in_sizes, int n_in,
                              void* d_out_, int out_size, void* d_ws, size_t ws_size,
                              hipStream_t stream) {
    (void)in_sizes; (void)n_in; (void)out_size; (void)ws_size;
    const float* x  = (const float*)d_in[0];
    const float* w1 = (const float*)d_in[1];
    const float* b1 = (const float*)d_in[2];
    const float* w2 = (const float*)d_in[3];
    const float* b2 = (const float*)d_in[4];
    const float* w3 = (const float*)d_in[5];
    const float* b3 = (const float*)d_in[6];
    const float* w4 = (const float*)d_in[7];
    const float* b4 = (const float*)d_in[8];
    const float* w5 = (const float*)d_in[9];
    const float* b5 = (const float*)d_in[10];
    const float* w6 = (const float*)d_in[11];
    const float* b6 = (const float*)d_in[12];
    float* dout = (float*)d_out_;

    char* ws = (char*)d_ws;
    float*  x123t    = (float*)(ws + 0);           // 25,165,824 B
    int*    idxb     = (int*)(ws + 25165824);      //  2,621,440 B
    float*  wbuf     = (float*)(ws + 27787264);    //     99,840 B
    float*  nrm      = (float*)(ws + 27887104);    //    131,072 B
    float*  partial6 = (float*)(ws + 28018176);    //  2,097,152 B
    double* wd2      = (double*)(ws + 30115328);   //     69,632 B

    prep_wf<<<1, 256, 0, stream>>>(w1, w2, w3, w4, w5, wbuf);
    prep_cmp<<<1, 256, 0, stream>>>(w1, b1, w2, b2, w3, b3, w4, b4, wd2);

    // ---- block 1 ----
    knn1_k<<<dim3(1024, BB), 128, 0, stream>>>(x, idxb);
    conv1_k<<<8192, 256, 0, stream>>>(x, idxb, wd2, dout, x123t);

    // ---- block 2 ----
    norms23_k<<<128, 256, 0, stream>>>(x123t, 0, nrm);
    knn23g_k<<<dim3(256, BB), 256, 0, stream>>>(x123t, dout, 0, nrm, idxb);
    conv2_k<<<8192, 256, 0, stream>>>(x123t, idxb, wd2, dout, x123t);

    // ---- block 3 ----
    norms23_k<<<128, 256, 0, stream>>>(x123t, 64, nrm);
    knn23g_k<<<dim3(256, BB), 256, 0, stream>>>(x123t, dout, 64, nrm, idxb);
    conv3_k<<<8192, 256, 0, stream>>>(x123t, idxb, wbuf, b5, dout, x123t);

    // ---- final conv1d + global max ----
    w6_k<<<8192, 256, 0, stream>>>(x123t, w6, partial6);
    final_k<<<64, 256, 0, stream>>>(partial6, b6, dout);
}

// Round 13
// 1743.998 us; speedup vs baseline: 12.2928x; 1.4478x over previous
//
#include <hip/hip_runtime.h>

// Problem constants
#define BB 16
#define NN 2048
#define KK 20

#define NEG_INF (-3.402823466e+38f)
#define DNEG (-1.0e300)

// ---------------------------------------------------------------------------
// Weight prep (f32 transposes, used by conv3): offsets in wb:
//   w5lo[64][64]@16768 w5hi[64][64]@20864
// ---------------------------------------------------------------------------
__global__ void prep_wf(const float* __restrict__ w1, const float* __restrict__ w2,
                        const float* __restrict__ w3, const float* __restrict__ w4,
                        const float* __restrict__ w5, float* __restrict__ wb) {
    int t = threadIdx.x;
    for (int i = t; i < 4096; i += 256) {
        int a = i >> 6, q = i & 63;
        wb[16768 + i] = w5[q * 128 + a];       // w5lo[c=a][o=q]
        wb[20864 + i] = w5[q * 128 + 64 + a];  // w5hi[c=a][o=q]
    }
}

// ---------------------------------------------------------------------------
// Composed fp64 weights:
//  M1[3][64]@0  Mh1[3][64]@192  g01[64]@384
//  M2[64][64]@448  Mh2[64][64]@4544  g02[64]@8640     (8704 doubles)
// ---------------------------------------------------------------------------
__global__ void prep_cmp(const float* __restrict__ w1, const float* __restrict__ b1,
                         const float* __restrict__ w2, const float* __restrict__ b2,
                         const float* __restrict__ w3, const float* __restrict__ b3,
                         const float* __restrict__ w4, const float* __restrict__ b4,
                         double* __restrict__ wd2) {
    int t = threadIdx.x;
    for (int i = t; i < 192; i += 256) {
        int c = i >> 6, o = i & 63;
        double s = 0, sh = 0;
        for (int j = 0; j < 64; ++j) {
            double w2v = (double)w2[o * 64 + j];
            s  = fma(w2v, (double)w1[j * 6 + c], s);
            sh = fma(w2v, (double)w1[j * 6 + 3 + c], sh);
        }
        wd2[i] = s;
        wd2[192 + i] = sh;
    }
    for (int i = t; i < 64; i += 256) {
        double s = (double)b2[i];
        for (int j = 0; j < 64; ++j)
            s = fma((double)w2[i * 64 + j], (double)b1[j], s);
        wd2[384 + i] = s;
        double s2 = (double)b4[i];
        for (int j = 0; j < 64; ++j)
            s2 = fma((double)w4[i * 64 + j], (double)b3[j], s2);
        wd2[8640 + i] = s2;
    }
    for (int i = t; i < 4096; i += 256) {
        int c = i >> 6, o = i & 63;
        double s = 0, sh = 0;
        for (int j = 0; j < 64; ++j) {
            double w4v = (double)w4[o * 64 + j];
            s  = fma(w4v, (double)w3[j * 128 + c], s);
            sh = fma(w4v, (double)w3[j * 128 + 64 + c], sh);
        }
        wd2[448 + i] = s;    // M2[c][o]
        wd2[4544 + i] = sh;  // Mh2[c][o]
    }
}

// ---------------------------------------------------------------------------
// Top-20 selection over 2048 f32 candidates in a per-wave LDS row.
// FROZEN: stable ties -> lowest index.
// ---------------------------------------------------------------------------
__device__ __forceinline__ void top2_upd(float v, int g, float& av, int& ai,
                                         float& bv, int& bi) {
    bool gta = v > av;
    bool gtb = v > bv;
    float nbv = gta ? av : (gtb ? v : bv);
    int   nbi = gta ? ai : (gtb ? g : bi);
    av = gta ? v : av;
    ai = gta ? g : ai;
    bv = nbv;
    bi = nbi;
}

__device__ __forceinline__ void topk20_run(float* vrow, int lane, float av, int ai,
                                           float bv, int bi, int* outp) {
    int myout = 0;
    #pragma unroll 1
    for (int it = 0; it < 20; ++it) {
        float wv = av;
        #pragma unroll
        for (int d = 32; d; d >>= 1) wv = fmaxf(wv, __shfl_xor(wv, d));
        unsigned long long bal = __ballot(av == wv);
        int widx;
        if (__popcll(bal) == 1) {
            widx = __shfl(ai, __ffsll(bal) - 1);
        } else {  // exact tie across lanes: lowest global index wins
            int tt = (av == wv) ? ai : 0x7fffffff;
            #pragma unroll
            for (int d = 32; d; d >>= 1) tt = min(tt, __shfl_xor(tt, d));
            widx = tt;
        }
        if (lane == it) myout = widx;
        if (lane == 0) vrow[widx] = NEG_INF;   // remove winner
        if (ai == widx) { av = bv; ai = bi; bv = NEG_INF; bi = 0x7fffffff; }
        if (av == NEG_INF) {                   // rare: lane's top-2 exhausted
            ai = 0x7fffffff; bv = NEG_INF; bi = 0x7fffffff;
            #pragma unroll 1
            for (int s = 0; s < 32; ++s) {
                int col = s * 64 + lane;
                top2_upd(vrow[col], col, av, ai, bv, bi);
            }
        }
    }
    if (lane < 20) outp[lane] = myout;
}

// ---------------------------------------------------------------------------
// knn1: numpy-f32 mirror, FROZEN arithmetic.
// ---------------------------------------------------------------------------
__global__ void knn1_k(const float* __restrict__ x, int* __restrict__ idx) {
    __shared__ float vlds[2][2048];
    int lane = threadIdx.x & 63, w = threadIdx.x >> 6;
    int b = blockIdx.y, r = blockIdx.x * 2 + w;
    const float* xb = x + (size_t)b * 3 * NN;
    float rx = xb[r], ry = xb[NN + r], rz = xb[2 * NN + r];
    float xxi = __fadd_rn(__fadd_rn(__fmul_rn(rx, rx), __fmul_rn(ry, ry)),
                          __fmul_rn(rz, rz));
    float* vrow = vlds[w];
    float av = NEG_INF, bv = NEG_INF;
    int ai = 0x7fffffff, bi = 0x7fffffff;
    #pragma unroll 1
    for (int s = 0; s < 32; ++s) {
        int col = s * 64 + lane;
        float cx = xb[col], cy = xb[NN + col], cz = xb[2 * NN + col];
        float xxj = __fadd_rn(__fadd_rn(__fmul_rn(cx, cx), __fmul_rn(cy, cy)),
                              __fmul_rn(cz, cz));
        float dot = fmaf(rz, cz, fmaf(ry, cy, __fmul_rn(rx, cx)));
        float inner = __fmul_rn(-2.f, dot);
        float t1 = __fsub_rn(-xxj, inner);
        float nd = __fsub_rn(t1, xxi);
        vrow[col] = nd;
        top2_upd(nd, col, av, ai, bv, bi);
    }
    topk20_run(vrow, lane, av, ai, bv, bi, idx + ((size_t)b * NN + r) * KK);
}

// xx for a 64-channel slice. FROZEN.
__global__ void norms23_k(const float* __restrict__ x123t, int coff,
                          float* __restrict__ nrm) {
    int t = blockIdx.x * 256 + threadIdx.x;   // 32768 points
    const float* r = x123t + (size_t)t * 192 + coff;
    float acc = 0.f;
    #pragma unroll 1
    for (int c = 0; c < 64; ++c)
        acc = __fadd_rn(acc, __fmul_rn(r[c], r[c]));
    nrm[t] = acc;
}

// ---------------------------------------------------------------------------
// pd GEMM (knn2/3 distances): 64x64 output tile per block, K=64 single tile.
// Each acc[i][j] gets one fmaf per ascending c  -> FROZEN chain preserved.
// Epilogue: frozen inner/t1/nd sequence. Inputs from channel-major dout slab.
// ---------------------------------------------------------------------------
__global__ __launch_bounds__(256) void gemm_pd_k(const float* __restrict__ dout,
        int coff, const float* __restrict__ nrm, float* __restrict__ pd, int b0) {
    __shared__ float As[64][68];
    __shared__ float Bs[64][68];
    int b = b0 + blockIdx.z;
    int rb = blockIdx.y * 64, cb = blockIdx.x * 64;
    const float* doutc = dout + (size_t)(b * 192 + coff) * NN;
    int tid = threadIdx.x;
    int cq = tid >> 4, qd = (tid & 15) * 4;
    #pragma unroll
    for (int cc = 0; cc < 64; cc += 16) {
        float4 a = *(const float4*)(doutc + (size_t)(cc + cq) * NN + rb + qd);
        As[cc + cq][qd + 0] = a.x; As[cc + cq][qd + 1] = a.y;
        As[cc + cq][qd + 2] = a.z; As[cc + cq][qd + 3] = a.w;
        float4 bv = *(const float4*)(doutc + (size_t)(cc + cq) * NN + cb + qd);
        Bs[cc + cq][qd + 0] = bv.x; Bs[cc + cq][qd + 1] = bv.y;
        Bs[cc + cq][qd + 2] = bv.z; Bs[cc + cq][qd + 3] = bv.w;
    }
    __syncthreads();
    int tx = tid & 15, ty = tid >> 4;
    float acc[4][4];
    #pragma unroll
    for (int i = 0; i < 4; ++i)
        #pragma unroll
        for (int j = 0; j < 4; ++j) acc[i][j] = 0.f;
    #pragma unroll 4
    for (int c = 0; c < 64; ++c) {
        float4 av4 = *(const float4*)&As[c][ty * 4];
        float4 bv4 = *(const float4*)&Bs[c][tx * 4];
        float aa[4] = {av4.x, av4.y, av4.z, av4.w};
        float bb[4] = {bv4.x, bv4.y, bv4.z, bv4.w};
        #pragma unroll
        for (int i = 0; i < 4; ++i)
            #pragma unroll
            for (int j = 0; j < 4; ++j)
                acc[i][j] = fmaf(aa[i], bb[j], acc[i][j]);  // ascending-c chain
    }
    const float* nb_ = nrm + (size_t)b * NN;
    #pragma unroll
    for (int i = 0; i < 4; ++i) {
        int r = rb + ty * 4 + i;
        float xxi = nb_[r];
        float4 o4;
        float* o = (float*)&o4;
        #pragma unroll
        for (int j = 0; j < 4; ++j) {
            float xxj = nb_[cb + tx * 4 + j];
            float inner = __fmul_rn(-2.f, acc[i][j]);
            float t1 = __fsub_rn(-xxj, inner);
            o[j] = __fsub_rn(t1, xxi);
        }
        *(float4*)(pd + ((size_t)blockIdx.z * NN + r) * NN + cb + tx * 4) = o4;
    }
}

// selection from materialized pd chunk (same frozen helpers as knn1)
__global__ void select_k(const float* __restrict__ pd, int* __restrict__ idx, int b0) {
    __shared__ float vlds[4][2048];
    int lane = threadIdx.x & 63, w = threadIdx.x >> 6;
    int bb = blockIdx.y, r = blockIdx.x * 4 + w;
    const float* row = pd + ((size_t)bb * NN + r) * NN;
    float* vrow = vlds[w];
    float av = NEG_INF, bv = NEG_INF;
    int ai = 0x7fffffff, bi = 0x7fffffff;
    #pragma unroll 1
    for (int s = 0; s < 32; ++s) {
        int col = s * 64 + lane;
        float v = row[col];
        vrow[col] = v;
        top2_upd(v, col, av, ai, bv, bi);
    }
    topk20_run(vrow, lane, av, ai, bv, bi, idx + ((size_t)(b0 + bb) * NN + r) * KK);
}

// ---------------------------------------------------------------------------
// EdgeConv blocks with composed fp64 weights + neighbor prefetch.
// ---------------------------------------------------------------------------
__global__ __launch_bounds__(256) void conv1_k(const float* __restrict__ x,
        const int* __restrict__ idxb, const double* __restrict__ wd2,
        float* __restrict__ dout, float* __restrict__ x123t) {
    int tid = threadIdx.x, lane = tid & 63, w = tid >> 6;
    int p = blockIdx.x * 4 + w, b = p >> 11, n = p & 2047;
    const float* xb = x + (size_t)b * 3 * NN;
    double c0 = (double)xb[n], c1 = (double)xb[NN + n], c2 = (double)xb[2 * NN + n];
    double m10 = wd2[lane], m11 = wd2[64 + lane], m12 = wd2[128 + lane];
    double g = wd2[384 + lane];
    g = fma(wd2[192 + lane], c0, g);
    g = fma(wd2[256 + lane], c1, g);
    g = fma(wd2[320 + lane], c2, g);
    const int* ip = idxb + (size_t)p * KK;
    int nb = ip[0];
    float f0 = xb[nb], f1 = xb[NN + nb], f2 = xb[2 * NN + nb];
    double m = DNEG;
    #pragma unroll 1
    for (int kk = 0; kk < KK; ++kk) {
        double d0 = (double)f0 - c0, d1 = (double)f1 - c1, d2 = (double)f2 - c2;
        if (kk < KK - 1) {
            int nb2 = ip[kk + 1];
            f0 = xb[nb2]; f1 = xb[NN + nb2]; f2 = xb[2 * NN + nb2];
        }
        double h = g;
        h = fma(m10, d0, h);
        h = fma(m11, d1, h);
        h = fma(m12, d2, h);
        m = fmax(m, h);
    }
    dout[((size_t)b * 192 + lane) * NN + n] = (float)m;
    x123t[((size_t)b * NN + n) * 192 + lane] = (float)m;
}

__global__ __launch_bounds__(256) void conv2_k(const float* __restrict__ x123t,
        const int* __restrict__ idxb, const double* __restrict__ wd2,
        float* __restrict__ dout, float* __restrict__ x123t_o) {
    __shared__ double M2s[4096];   // 32 KB
    __shared__ double dbs[4][64];  // 2 KB
    int tid = threadIdx.x, lane = tid & 63, w = tid >> 6;
    for (int i = tid; i < 4096; i += 256) M2s[i] = wd2[448 + i];
    __syncthreads();
    int p = blockIdx.x * 4 + w, b = p >> 11, n = p & 2047;
    const float* base = x123t + (size_t)b * NN * 192;
    double ctr = (double)base[(size_t)n * 192 + lane];
    dbs[w][lane] = ctr;
    double g = wd2[8640 + lane];
    #pragma unroll 4
    for (int c = 0; c < 64; ++c)
        g = fma(wd2[4544 + c * 64 + lane], dbs[w][c], g);
    const int* ip = idxb + (size_t)p * KK;
    int nb = ip[0];
    float nbreg = base[(size_t)nb * 192 + lane];
    double m = DNEG;
    #pragma unroll 1
    for (int kk = 0; kk < KK; ++kk) {
        dbs[w][lane] = (double)nbreg - ctr;
        if (kk < KK - 1) {
            int nb2 = ip[kk + 1];
            nbreg = base[(size_t)nb2 * 192 + lane];
        }
        double a0 = g, a1 = 0, a2 = 0, a3 = 0;
        #pragma unroll
        for (int c = 0; c < 64; c += 4) {
            a0 = fma(M2s[(c + 0) * 64 + lane], dbs[w][c + 0], a0);
            a1 = fma(M2s[(c + 1) * 64 + lane], dbs[w][c + 1], a1);
            a2 = fma(M2s[(c + 2) * 64 + lane], dbs[w][c + 2], a2);
            a3 = fma(M2s[(c + 3) * 64 + lane], dbs[w][c + 3], a3);
        }
        m = fmax(m, (a0 + a1) + (a2 + a3));
    }
    dout[((size_t)b * 192 + 64 + lane) * NN + n] = (float)m;
    x123t_o[((size_t)b * NN + n) * 192 + 64 + lane] = (float)m;
}

__global__ __launch_bounds__(256) void conv3_k(const float* __restrict__ x123t,
        const int* __restrict__ idxb, const float* __restrict__ wb,
        const float* __restrict__ b5,
        float* __restrict__ dout, float* __restrict__ x123t_o) {
    __shared__ float w5s[4096];    // 16 KB
    __shared__ double dbs[4][64];  // 2 KB
    int tid = threadIdx.x, lane = tid & 63, w = tid >> 6;
    for (int i = tid; i < 4096; i += 256) w5s[i] = wb[16768 + i];
    __syncthreads();
    int p = blockIdx.x * 4 + w, b = p >> 11, n = p & 2047;
    const float* base = x123t + (size_t)b * NN * 192 + 64;  // x2 slice
    double ctr = (double)base[(size_t)n * 192 + lane];
    dbs[w][lane] = ctr;
    double h0 = (double)b5[lane], h1a = 0, h2a = 0, h3a = 0;
    #pragma unroll 4
    for (int c = 0; c < 64; c += 4) {
        h0  = fma((double)wb[20864 + (c + 0) * 64 + lane], dbs[w][c + 0], h0);
        h1a = fma((double)wb[20864 + (c + 1) * 64 + lane], dbs[w][c + 1], h1a);
        h2a = fma((double)wb[20864 + (c + 2) * 64 + lane], dbs[w][c + 2], h2a);
        h3a = fma((double)wb[20864 + (c + 3) * 64 + lane], dbs[w][c + 3], h3a);
    }
    double hc = (h0 + h1a) + (h2a + h3a);
    const int* ip = idxb + (size_t)p * KK;
    int nb = ip[0];
    float nbreg = base[(size_t)nb * 192 + lane];
    double m = DNEG;
    #pragma unroll 1
    for (int kk = 0; kk < KK; ++kk) {
        dbs[w][lane] = (double)nbreg - ctr;
        if (kk < KK - 1) {
            int nb2 = ip[kk + 1];
            nbreg = base[(size_t)nb2 * 192 + lane];
        }
        double a0 = hc, a1 = 0, a2 = 0, a3 = 0;
        #pragma unroll
        for (int c = 0; c < 64; c += 4) {
            a0 = fma((double)w5s[(c + 0) * 64 + lane], dbs[w][c + 0], a0);
            a1 = fma((double)w5s[(c + 1) * 64 + lane], dbs[w][c + 1], a1);
            a2 = fma((double)w5s[(c + 2) * 64 + lane], dbs[w][c + 2], a2);
            a3 = fma((double)w5s[(c + 3) * 64 + lane], dbs[w][c + 3], a3);
        }
        m = fmax(m, (a0 + a1) + (a2 + a3));
    }
    dout[((size_t)b * 192 + 128 + lane) * NN + n] = (float)m;
    x123t_o[((size_t)b * NN + n) * 192 + 128 + lane] = (float)m;
}

// ---------------------------------------------------------------------------
// Final conv1d (1024x192) as LDS-tiled f32 GEMM, 64o x 64n per block, KC=32.
// ---------------------------------------------------------------------------
#define KC 32
__global__ __launch_bounds__(256) void w6_k(const float* __restrict__ x123t,
                                            const float* __restrict__ w6,
                                            float* __restrict__ partial6) {
    __shared__ float xs[KC][68];
    __shared__ float wsb[KC][68];
    __shared__ float red[64][17];
    int tid = threadIdx.x;
    int ntile = blockIdx.x & 31, ot = (blockIdx.x >> 5) & 15, b = blockIdx.x >> 9;
    int n0 = ntile * 64, o0 = ot * 64;
    int ln = tid >> 2, lc = (tid & 3) * 8;
    const float* xrow = x123t + ((size_t)b * NN + n0 + ln) * 192 + lc;
    const float* wrow = w6 + (size_t)(o0 + ln) * 192 + lc;
    float acc[4][4];
    #pragma unroll
    for (int i = 0; i < 4; ++i)
        #pragma unroll
        for (int j = 0; j < 4; ++j) acc[i][j] = 0.f;
    int to = tid & 15, tn = tid >> 4;
    for (int cc = 0; cc < 192; cc += KC) {
        float4 xa = *(const float4*)(xrow + cc);
        float4 xb4 = *(const float4*)(xrow + cc + 4);
        float4 wa = *(const float4*)(wrow + cc);
        float4 wb4 = *(const float4*)(wrow + cc + 4);
        __syncthreads();
        xs[lc + 0][ln] = xa.x; xs[lc + 1][ln] = xa.y;
        xs[lc + 2][ln] = xa.z; xs[lc + 3][ln] = xa.w;
        xs[lc + 4][ln] = xb4.x; xs[lc + 5][ln] = xb4.y;
        xs[lc + 6][ln] = xb4.z; xs[lc + 7][ln] = xb4.w;
        wsb[lc + 0][ln] = wa.x; wsb[lc + 1][ln] = wa.y;
        wsb[lc + 2][ln] = wa.z; wsb[lc + 3][ln] = wa.w;
        wsb[lc + 4][ln] = wb4.x; wsb[lc + 5][ln] = wb4.y;
        wsb[lc + 6][ln] = wb4.z; wsb[lc + 7][ln] = wb4.w;
        __syncthreads();
        #pragma unroll
        for (int k = 0; k < KC; ++k) {
            float4 wv = *(const float4*)&wsb[k][to * 4];
            float4 xv = *(const float4*)&xs[k][tn * 4];
            float wr[4] = {wv.x, wv.y, wv.z, wv.w};
            float xr[4] = {xv.x, xv.y, xv.z, xv.w};
            #pragma unroll
            for (int i = 0; i < 4; ++i)
                #pragma unroll
                for (int j = 0; j < 4; ++j)
                    acc[i][j] = fmaf(wr[i], xr[j], acc[i][j]);
        }
    }
    #pragma unroll
    for (int i = 0; i < 4; ++i) {
        float mm = fmaxf(fmaxf(acc[i][0], acc[i][1]), fmaxf(acc[i][2], acc[i][3]));
        red[to * 4 + i][tn] = mm;
    }
    __syncthreads();
    if (tid < 64) {
        float mm = red[tid][0];
        #pragma unroll
        for (int t = 1; t < 16; ++t) mm = fmaxf(mm, red[tid][t]);
        partial6[((size_t)b * 1024 + o0 + tid) * 32 + ntile] = mm;
    }
}

__global__ void final_k(const float* __restrict__ partial6, const float* __restrict__ b6,
                        float* __restrict__ dout) {
    int t = blockIdx.x * 256 + threadIdx.x;  // < 16*1024
    int o = t & 1023;
    float m = NEG_INF;
    #pragma unroll 1
    for (int nt = 0; nt < 32; ++nt) m = fmaxf(m, partial6[(size_t)t * 32 + nt]);
    dout[(size_t)BB * 192 * NN + t] = m + b6[o];
}

// ---------------------------------------------------------------------------
extern "C" void kernel_launch(void* const* d_in, const int* in_sizes, int n_in,
                              void* d_out_, int out_size, void* d_ws, size_t ws_size,
                              hipStream_t stream) {
    (void)in_sizes; (void)n_in; (void)out_size;
    const float* x  = (const float*)d_in[0];
    const float* w1 = (const float*)d_in[1];
    const float* b1 = (const float*)d_in[2];
    const float* w2 = (const float*)d_in[3];
    const float* b2 = (const float*)d_in[4];
    const float* w3 = (const float*)d_in[5];
    const float* b3 = (const float*)d_in[6];
    const float* w4 = (const float*)d_in[7];
    const float* b4 = (const float*)d_in[8];
    const float* w5 = (const float*)d_in[9];
    const float* b5 = (const float*)d_in[10];
    const float* w6 = (const float*)d_in[11];
    const float* b6 = (const float*)d_in[12];
    float* dout = (float*)d_out_;

    char* ws = (char*)d_ws;
    float*  x123t    = (float*)(ws + 0);           // 25,165,824 B
    int*    idxb     = (int*)(ws + 25165824);      //  2,621,440 B
    float*  wbuf     = (float*)(ws + 27787264);    //     99,840 B
    float*  nrm      = (float*)(ws + 27887104);    //    131,072 B
    float*  partial6 = (float*)(ws + 28018176);    //  2,097,152 B
    double* wd2      = (double*)(ws + 30115328);   //     69,632 B
    float*  pd       = (float*)(ws + 30212096);    //  nb * 16 MiB
    long long avail = (long long)ws_size - 30212096LL;
    int nb = (int)(avail / 16777216LL);
    if (nb < 1) nb = 1;
    if (nb > 16) nb = 16;

    prep_wf<<<1, 256, 0, stream>>>(w1, w2, w3, w4, w5, wbuf);
    prep_cmp<<<1, 256, 0, stream>>>(w1, b1, w2, b2, w3, b3, w4, b4, wd2);

    // ---- block 1 ----
    knn1_k<<<dim3(1024, BB), 128, 0, stream>>>(x, idxb);
    conv1_k<<<8192, 256, 0, stream>>>(x, idxb, wd2, dout, x123t);

    // ---- knn on x1 (tiled GEMM + select, frozen arithmetic) ----
    norms23_k<<<128, 256, 0, stream>>>(x123t, 0, nrm);
    for (int b0 = 0; b0 < BB; b0 += nb) {
        int cur = (BB - b0 < nb) ? (BB - b0) : nb;
        gemm_pd_k<<<dim3(32, 32, cur), 256, 0, stream>>>(dout, 0, nrm, pd, b0);
        select_k<<<dim3(512, cur), 256, 0, stream>>>(pd, idxb, b0);
    }
    conv2_k<<<8192, 256, 0, stream>>>(x123t, idxb, wd2, dout, x123t);

    // ---- knn on x2 ----
    norms23_k<<<128, 256, 0, stream>>>(x123t, 64, nrm);
    for (int b0 = 0; b0 < BB; b0 += nb) {
        int cur = (BB - b0 < nb) ? (BB - b0) : nb;
        gemm_pd_k<<<dim3(32, 32, cur), 256, 0, stream>>>(dout, 64, nrm, pd, b0);
        select_k<<<dim3(512, cur), 256, 0, stream>>>(pd, idxb, b0);
    }
    conv3_k<<<8192, 256, 0, stream>>>(x123t, idxb, wbuf, b5, dout, x123t);

    // ---- final conv1d + global max ----
    w6_k<<<8192, 256, 0, stream>>>(x123t, w6, partial6);
    final_k<<<64, 256, 0, stream>>>(partial6, b6, dout);
}